// Round 1
// baseline (870.918 us; speedup 1.0000x reference)
//
#include <hip/hip_runtime.h>
#include <cstdint>
#include <cstddef>

namespace {

constexpr int N_NODES = 100000;
constexpr int N_EDGES = 1600000;
constexpr int NUM_GRAPHS = 128;
constexpr int F = 128;
constexpr float BN_EPS = 1e-5f;
constexpr int SCAN_NB = (N_NODES + 255) / 256;   // 391

// ---- edge sort (CSR by dst) ------------------------------------------------

__global__ void k_hist(const int* __restrict__ ei, int* __restrict__ deg) {
    int e = blockIdx.x * 256 + threadIdx.x;
    if (e < N_EDGES) atomicAdd(&deg[ei[N_EDGES + e]], 1);
}

__global__ void k_scan1(const int* __restrict__ deg, int* __restrict__ offs,
                        int* __restrict__ bsums) {
    __shared__ int tmp[256];
    int i = blockIdx.x * 256 + threadIdx.x;
    int v = (i < N_NODES) ? deg[i] : 0;
    tmp[threadIdx.x] = v;
    __syncthreads();
    #pragma unroll
    for (int d = 1; d < 256; d <<= 1) {
        int t = (threadIdx.x >= d) ? tmp[threadIdx.x - d] : 0;
        __syncthreads();
        tmp[threadIdx.x] += t;
        __syncthreads();
    }
    if (i < N_NODES) offs[i] = tmp[threadIdx.x] - v;   // exclusive within block
    if (threadIdx.x == 255) bsums[blockIdx.x] = tmp[255];
}

__global__ void k_scan2(int* __restrict__ bsums) {
    __shared__ int tmp[512];
    int i = threadIdx.x;
    int v = (i < SCAN_NB) ? bsums[i] : 0;
    tmp[i] = v;
    __syncthreads();
    #pragma unroll
    for (int d = 1; d < 512; d <<= 1) {
        int t = (i >= d) ? tmp[i - d] : 0;
        __syncthreads();
        tmp[i] += t;
        __syncthreads();
    }
    if (i < SCAN_NB) bsums[i] = tmp[i] - v;            // exclusive block offsets
}

__global__ void k_scan3(int* __restrict__ offs, const int* __restrict__ bsums) {
    int i = blockIdx.x * 256 + threadIdx.x;
    if (i < N_NODES) offs[i] += bsums[blockIdx.x];
    if (i == 0) offs[N_NODES] = N_EDGES;
}

__global__ void k_scatter(const int* __restrict__ ei, const int* __restrict__ offs,
                          int* __restrict__ cursor, int* __restrict__ ssrc) {
    int e = blockIdx.x * 256 + threadIdx.x;
    if (e >= N_EDGES) return;
    int d = ei[N_EDGES + e];
    int p = offs[d] + atomicAdd(&cursor[d], 1);
    ssrc[p] = ei[e];
}

// ---- graph segment boundaries (batch is sorted) ----------------------------

__global__ void k_bound(const int* __restrict__ batch, int* __restrict__ gstart) {
    int i = blockIdx.x * 256 + threadIdx.x;
    if (i >= N_NODES) return;
    int b = batch[i];
    if (i == 0) {
        for (int g = 0; g <= b; ++g) gstart[g] = 0;
    } else {
        int p = batch[i - 1];
        if (p != b) for (int g = p + 1; g <= b; ++g) gstart[g] = i;
    }
    if (i == N_NODES - 1) {
        for (int g = b + 1; g <= NUM_GRAPHS; ++g) gstart[g] = N_NODES;
    }
}

// ---- layer 1 ---------------------------------------------------------------

__global__ void k_agg1(const float* __restrict__ x, const int* __restrict__ offs,
                       const int* __restrict__ ssrc, float* __restrict__ agg1) {
    int n = blockIdx.x * 256 + threadIdx.x;
    if (n >= N_NODES) return;
    int s0 = offs[n], s1 = offs[n + 1];
    float a0=0,a1=0,a2=0,a3=0,a4=0,a5=0,a6=0,a7=0;
    for (int j = s0; j < s1; ++j) {
        const float4* xp = (const float4*)(x + (size_t)ssrc[j] * 8);
        float4 b0 = xp[0], b1 = xp[1];
        a0+=b0.x; a1+=b0.y; a2+=b0.z; a3+=b0.w;
        a4+=b1.x; a5+=b1.y; a6+=b1.z; a7+=b1.w;
    }
    int dg = s1 - s0;
    float inv = 1.0f / (float)(dg > 1 ? dg : 1);
    float4 o0 = {a0*inv, a1*inv, a2*inv, a3*inv};
    float4 o1 = {a4*inv, a5*inv, a6*inv, a7*inv};
    float4* op = (float4*)(agg1 + (size_t)n * 8);
    op[0] = o0; op[1] = o1;
}

// h1 = agg1 @ W1l^T + b1 + x @ W1r^T ; fused BN-stat accumulation
__global__ void __launch_bounds__(128) k_lin1(
        const float* __restrict__ x, const float* __restrict__ agg1,
        const float* __restrict__ W1l, const float* __restrict__ b1,
        const float* __restrict__ W1r, float* __restrict__ h1,
        float* __restrict__ stats) {
    int f = threadIdx.x;                       // 128 features
    float4 wl0 = *(const float4*)(W1l + f * 8);
    float4 wl1 = *(const float4*)(W1l + f * 8 + 4);
    float4 wr0 = *(const float4*)(W1r + f * 8);
    float4 wr1 = *(const float4*)(W1r + f * 8 + 4);
    float bb = b1[f];
    int n0 = blockIdx.x * 32;                  // N divisible by 32
    float s = 0.f, s2 = 0.f;
    for (int n = n0; n < n0 + 32; ++n) {
        const float4* ap = (const float4*)(agg1 + (size_t)n * 8);
        const float4* xp = (const float4*)(x + (size_t)n * 8);
        float4 a0 = ap[0], a1 = ap[1], x0 = xp[0], x1v = xp[1];
        float acc = bb;
        acc += a0.x*wl0.x + a0.y*wl0.y + a0.z*wl0.z + a0.w*wl0.w;
        acc += a1.x*wl1.x + a1.y*wl1.y + a1.z*wl1.z + a1.w*wl1.w;
        acc += x0.x*wr0.x + x0.y*wr0.y + x0.z*wr0.z + x0.w*wr0.w;
        acc += x1v.x*wr1.x + x1v.y*wr1.y + x1v.z*wr1.z + x1v.w*wr1.w;
        h1[(size_t)n * F + f] = acc;
        s += acc; s2 += acc * acc;
    }
    atomicAdd(&stats[f], s);
    atomicAdd(&stats[F + f], s2);
}

// fold BN into per-feature scale/shift
__global__ void k_bnfin(const float* __restrict__ stats, const float* __restrict__ gamma,
                        const float* __restrict__ beta, float* __restrict__ scsh) {
    int f = threadIdx.x;
    float mu  = stats[f] * (1.0f / N_NODES);
    float var = stats[F + f] * (1.0f / N_NODES) - mu * mu;
    float sc  = gamma[f] * rsqrtf(var + BN_EPS);
    scsh[f] = sc;
    scsh[F + f] = beta[f] - mu * sc;
}

// x1 = relu(scale*h1 + shift), in place
__global__ void k_bnrelu(float* __restrict__ h, const float* __restrict__ scsh) {
    size_t i = ((size_t)blockIdx.x * 256 + threadIdx.x) * 4;   // exact grid
    int f = (int)(i & (F - 1));
    float4 v = *(float4*)(h + i);
    v.x = fmaxf(0.f, v.x * scsh[f]     + scsh[F + f]);
    v.y = fmaxf(0.f, v.y * scsh[f + 1] + scsh[F + f + 1]);
    v.z = fmaxf(0.f, v.z * scsh[f + 2] + scsh[F + f + 2]);
    v.w = fmaxf(0.f, v.w * scsh[f + 3] + scsh[F + f + 3]);
    *(float4*)(h + i) = v;
}

// ---- layer 2 ---------------------------------------------------------------

// agg2[n][f] = mean over in-edges of x1[src][f]; block = 2 nodes x 128 feats
__global__ void __launch_bounds__(256) k_agg2(
        const float* __restrict__ x1, const int* __restrict__ offs,
        const int* __restrict__ ssrc, float* __restrict__ agg2) {
    int n = blockIdx.x * 2 + (threadIdx.x >> 7);
    int f = threadIdx.x & 127;
    int s0 = offs[n], s1 = offs[n + 1];
    float acc = 0.f;
    int j = s0;
    for (; j + 1 < s1; j += 2) {       // 2 gathers in flight
        int sa = ssrc[j], sb = ssrc[j + 1];
        float va = x1[(size_t)sa * F + f];
        float vb = x1[(size_t)sb * F + f];
        acc += va; acc += vb;
    }
    if (j < s1) acc += x1[(size_t)ssrc[j] * F + f];
    int dg = s1 - s0;
    agg2[(size_t)n * F + f] = acc * (1.0f / (float)(dg > 1 ? dg : 1));
}

__global__ void k_transp(const float* __restrict__ W, float* __restrict__ WT) {
    int i = blockIdx.x * 256 + threadIdx.x;    // 16384 exact
    int r = i >> 7, c = i & 127;
    WT[c * F + r] = W[i];
}

// h2 = agg2 @ W2l^T + b2 + x1 @ W2r^T ; 8 nodes x 128 feats per block
__global__ void __launch_bounds__(128) k_lin2(
        const float* __restrict__ agg2, const float* __restrict__ x1,
        const float* __restrict__ WlT, const float* __restrict__ WrT,
        const float* __restrict__ b2, float* __restrict__ h2) {
    int f = threadIdx.x;
    int n0 = blockIdx.x * 8;                   // N divisible by 8
    float acc[8] = {0,0,0,0,0,0,0,0};
    for (int k = 0; k < F; k += 4) {
        float wl0 = WlT[(k + 0) * F + f];
        float wl1 = WlT[(k + 1) * F + f];
        float wl2 = WlT[(k + 2) * F + f];
        float wl3 = WlT[(k + 3) * F + f];
        float wr0 = WrT[(k + 0) * F + f];
        float wr1 = WrT[(k + 1) * F + f];
        float wr2 = WrT[(k + 2) * F + f];
        float wr3 = WrT[(k + 3) * F + f];
        #pragma unroll
        for (int i = 0; i < 8; ++i) {
            // block-uniform addresses -> scalar (s_load) broadcasts
            const float4 a  = *(const float4*)(agg2 + (size_t)(n0 + i) * F + k);
            const float4 xx = *(const float4*)(x1   + (size_t)(n0 + i) * F + k);
            acc[i] += a.x * wl0 + a.y * wl1 + a.z * wl2 + a.w * wl3
                    + xx.x * wr0 + xx.y * wr1 + xx.z * wr2 + xx.w * wr3;
        }
    }
    float bb = b2[f];
    #pragma unroll
    for (int i = 0; i < 8; ++i)
        h2[(size_t)(n0 + i) * F + f] = acc[i] + bb;
}

__global__ void k_stats(const float* __restrict__ h, float* __restrict__ stats) {
    int f = threadIdx.x;
    int n0 = blockIdx.x * 128;
    int n1 = min(n0 + 128, N_NODES);
    float s = 0.f, s2 = 0.f;
    for (int n = n0; n < n1; ++n) {
        float v = h[(size_t)n * F + f];
        s += v; s2 += v * v;
    }
    atomicAdd(&stats[f], s);
    atomicAdd(&stats[F + f], s2);
}

// ---- pooling ---------------------------------------------------------------

// h = x1 + relu(scale2*h2 + shift2); per-graph running sums, flush on change
__global__ void k_pool(const float* __restrict__ x1, const float* __restrict__ h2,
                       const float* __restrict__ scsh2, const int* __restrict__ batch,
                       float* __restrict__ outacc) {
    int f = threadIdx.x;
    int n0 = blockIdx.x * 128;
    int n1 = min(n0 + 128, N_NODES);
    float sc = scsh2[f], sh = scsh2[F + f];
    float acc = 0.f;
    int curg = batch[n0];
    for (int n = n0; n < n1; ++n) {
        int g = batch[n];
        if (g != curg) {
            atomicAdd(&outacc[curg * F + f], acc);
            acc = 0.f; curg = g;
        }
        float v1 = x1[(size_t)n * F + f];
        float v2 = fmaxf(0.f, h2[(size_t)n * F + f] * sc + sh);
        acc += v1 + v2;
    }
    atomicAdd(&outacc[curg * F + f], acc);
}

__global__ void k_out(const float* __restrict__ outacc, const int* __restrict__ gstart,
                      float* __restrict__ out) {
    int i = blockIdx.x * 256 + threadIdx.x;
    if (i >= NUM_GRAPHS * F) return;
    int g = i >> 7;
    int c = gstart[g + 1] - gstart[g];
    out[i] = outacc[i] / (float)(c > 1 ? c : 1);
}

}  // namespace

extern "C" void kernel_launch(void* const* d_in, const int* in_sizes, int n_in,
                              void* d_out, int out_size, void* d_ws, size_t ws_size,
                              hipStream_t stream) {
    const float* x     = (const float*)d_in[0];
    const int*   ei    = (const int*)d_in[1];    // [2, E]: row0 = src, row1 = dst
    const int*   batch = (const int*)d_in[2];
    const float* W1l   = (const float*)d_in[3];
    const float* b1    = (const float*)d_in[4];
    const float* W1r   = (const float*)d_in[5];
    const float* g1    = (const float*)d_in[6];
    const float* be1   = (const float*)d_in[7];
    const float* W2l   = (const float*)d_in[8];
    const float* b2    = (const float*)d_in[9];
    const float* W2r   = (const float*)d_in[10];
    const float* g2    = (const float*)d_in[11];
    const float* be2   = (const float*)d_in[12];
    float* out = (float*)d_out;

    char* w = (char*)d_ws;
    size_t o = 0;
    auto alloc = [&](size_t bytes) {
        void* p = w + o;
        o += (bytes + 511) & ~(size_t)511;
        return p;
    };
    int*   deg    = (int*)alloc((size_t)N_NODES * 4);
    int*   offs   = (int*)alloc((size_t)(N_NODES + 1) * 4);
    int*   cursor = (int*)alloc((size_t)N_NODES * 4);
    int*   ssrc   = (int*)alloc((size_t)N_EDGES * 4);
    int*   bsums  = (int*)alloc(2048);
    int*   gstart = (int*)alloc((NUM_GRAPHS + 1) * 4);
    float* stats  = (float*)alloc(512 * 4);   // [s1,s1sq | s2,s2sq]
    float* scsh   = (float*)alloc(512 * 4);   // [sc1,sh1 | sc2,sh2]
    float* WlT    = (float*)alloc((size_t)F * F * 4);
    float* WrT    = (float*)alloc((size_t)F * F * 4);
    float* outacc = (float*)alloc((size_t)NUM_GRAPHS * F * 4);
    float* agg1   = (float*)alloc((size_t)N_NODES * 8 * 4);
    float* x1     = (float*)alloc((size_t)N_NODES * F * 4);   // h1 -> x1 in place
    float* agg2   = (float*)alloc((size_t)N_NODES * F * 4);
    float* h2     = (float*)alloc((size_t)N_NODES * F * 4);

    hipMemsetAsync(deg,    0, (size_t)N_NODES * 4, stream);
    hipMemsetAsync(cursor, 0, (size_t)N_NODES * 4, stream);
    hipMemsetAsync(stats,  0, 512 * 4, stream);
    hipMemsetAsync(outacc, 0, (size_t)NUM_GRAPHS * F * 4, stream);

    // CSR-by-dst edge sort + graph boundaries + weight transpose
    k_hist   <<<(N_EDGES + 255) / 256, 256, 0, stream>>>(ei, deg);
    k_scan1  <<<SCAN_NB, 256, 0, stream>>>(deg, offs, bsums);
    k_scan2  <<<1, 512, 0, stream>>>(bsums);
    k_scan3  <<<SCAN_NB, 256, 0, stream>>>(offs, bsums);
    k_scatter<<<(N_EDGES + 255) / 256, 256, 0, stream>>>(ei, offs, cursor, ssrc);
    k_bound  <<<(N_NODES + 255) / 256, 256, 0, stream>>>(batch, gstart);
    k_transp <<<64, 256, 0, stream>>>(W2l, WlT);
    k_transp <<<64, 256, 0, stream>>>(W2r, WrT);

    // layer 1
    k_agg1  <<<(N_NODES + 255) / 256, 256, 0, stream>>>(x, offs, ssrc, agg1);
    k_lin1  <<<N_NODES / 32, 128, 0, stream>>>(x, agg1, W1l, b1, W1r, x1, stats);
    k_bnfin <<<1, 128, 0, stream>>>(stats, g1, be1, scsh);
    k_bnrelu<<<(N_NODES * F / 4) / 256, 256, 0, stream>>>(x1, scsh);

    // layer 2
    k_agg2  <<<N_NODES / 2, 256, 0, stream>>>(x1, offs, ssrc, agg2);
    k_lin2  <<<N_NODES / 8, 128, 0, stream>>>(agg2, x1, WlT, WrT, b2, h2);
    k_stats <<<(N_NODES + 127) / 128, 128, 0, stream>>>(h2, stats + 256);
    k_bnfin <<<1, 128, 0, stream>>>(stats + 256, g2, be2, scsh + 256);

    // residual + pool
    k_pool<<<(N_NODES + 127) / 128, 128, 0, stream>>>(x1, h2, scsh + 256, batch, outacc);
    k_out <<<(NUM_GRAPHS * F + 255) / 256, 256, 0, stream>>>(outacc, gstart, out);
}

// Round 2
// 704.751 us; speedup vs baseline: 1.2358x; 1.2358x over previous
//
#include <hip/hip_runtime.h>
#include <cstdint>
#include <cstddef>

namespace {

constexpr int N_NODES = 100000;
constexpr int N_EDGES = 1600000;
constexpr int NUM_GRAPHS = 128;
constexpr int F = 128;
constexpr float BN_EPS = 1e-5f;
constexpr int SCAN_NB = (N_NODES + 255) / 256;   // 391
constexpr int ROWF = 132;                        // padded LDS row (528B, 16B-aligned)

// ---- edge sort (CSR by dst) ------------------------------------------------

__global__ void k_hist(const int* __restrict__ ei, int* __restrict__ deg) {
    int e = blockIdx.x * 256 + threadIdx.x;
    if (e < N_EDGES) atomicAdd(&deg[ei[N_EDGES + e]], 1);
}

__global__ void k_scan1(const int* __restrict__ deg, int* __restrict__ offs,
                        int* __restrict__ bsums) {
    __shared__ int tmp[256];
    int i = blockIdx.x * 256 + threadIdx.x;
    int v = (i < N_NODES) ? deg[i] : 0;
    tmp[threadIdx.x] = v;
    __syncthreads();
    #pragma unroll
    for (int d = 1; d < 256; d <<= 1) {
        int t = (threadIdx.x >= d) ? tmp[threadIdx.x - d] : 0;
        __syncthreads();
        tmp[threadIdx.x] += t;
        __syncthreads();
    }
    if (i < N_NODES) offs[i] = tmp[threadIdx.x] - v;   // exclusive within block
    if (threadIdx.x == 255) bsums[blockIdx.x] = tmp[255];
}

__global__ void k_scan2(int* __restrict__ bsums) {
    __shared__ int tmp[512];
    int i = threadIdx.x;
    int v = (i < SCAN_NB) ? bsums[i] : 0;
    tmp[i] = v;
    __syncthreads();
    #pragma unroll
    for (int d = 1; d < 512; d <<= 1) {
        int t = (i >= d) ? tmp[i - d] : 0;
        __syncthreads();
        tmp[i] += t;
        __syncthreads();
    }
    if (i < SCAN_NB) bsums[i] = tmp[i] - v;            // exclusive block offsets
}

__global__ void k_scan3(int* __restrict__ offs, const int* __restrict__ bsums) {
    int i = blockIdx.x * 256 + threadIdx.x;
    if (i < N_NODES) offs[i] += bsums[blockIdx.x];
    if (i == 0) offs[N_NODES] = N_EDGES;
}

__global__ void k_scatter(const int* __restrict__ ei, const int* __restrict__ offs,
                          int* __restrict__ cursor, int* __restrict__ ssrc) {
    int e = blockIdx.x * 256 + threadIdx.x;
    if (e >= N_EDGES) return;
    int d = ei[N_EDGES + e];
    int p = offs[d] + atomicAdd(&cursor[d], 1);
    ssrc[p] = ei[e];
}

// ---- graph segment boundaries (batch is sorted) ----------------------------

__global__ void k_bound(const int* __restrict__ batch, int* __restrict__ gstart) {
    int i = blockIdx.x * 256 + threadIdx.x;
    if (i >= N_NODES) return;
    int b = batch[i];
    if (i == 0) {
        for (int g = 0; g <= b; ++g) gstart[g] = 0;
    } else {
        int p = batch[i - 1];
        if (p != b) for (int g = p + 1; g <= b; ++g) gstart[g] = i;
    }
    if (i == N_NODES - 1) {
        for (int g = b + 1; g <= NUM_GRAPHS; ++g) gstart[g] = N_NODES;
    }
}

// ---- weight repack: Wp[k>>2][f][k&3] = W[f][k]  (float4 over k per thread) --

__global__ void k_pack(const float* __restrict__ W, float* __restrict__ Wp) {
    int i = blockIdx.x * 256 + threadIdx.x;    // 16384 exact
    int fi = i >> 7, k = i & 127;
    Wp[(size_t)((k >> 2) * 128 + fi) * 4 + (k & 3)] = W[i];
}

// ---- layer 1 ---------------------------------------------------------------

__global__ void k_agg1(const float* __restrict__ x, const int* __restrict__ offs,
                       const int* __restrict__ ssrc, float* __restrict__ agg1) {
    int n = blockIdx.x * 256 + threadIdx.x;
    if (n >= N_NODES) return;
    int s0 = offs[n], s1 = offs[n + 1];
    float a0=0,a1=0,a2=0,a3=0,a4=0,a5=0,a6=0,a7=0;
    for (int j = s0; j < s1; ++j) {
        const float4* xp = (const float4*)(x + (size_t)ssrc[j] * 8);
        float4 b0 = xp[0], b1 = xp[1];
        a0+=b0.x; a1+=b0.y; a2+=b0.z; a3+=b0.w;
        a4+=b1.x; a5+=b1.y; a6+=b1.z; a7+=b1.w;
    }
    int dg = s1 - s0;
    float inv = 1.0f / (float)(dg > 1 ? dg : 1);
    float4 o0 = {a0*inv, a1*inv, a2*inv, a3*inv};
    float4 o1 = {a4*inv, a5*inv, a6*inv, a7*inv};
    float4* op = (float4*)(agg1 + (size_t)n * 8);
    op[0] = o0; op[1] = o1;
}

// h1 = agg1 @ W1l^T + b1 + x @ W1r^T ; node rows staged in LDS (broadcast reads)
__global__ void __launch_bounds__(128) k_lin1(
        const float* __restrict__ x, const float* __restrict__ agg1,
        const float* __restrict__ W1l, const float* __restrict__ b1,
        const float* __restrict__ W1r, float* __restrict__ h1,
        float* __restrict__ stats) {
    __shared__ float sN[32 * 16];              // per node: [x 0..7 | agg1 8..15]
    int tid = threadIdx.x, f = tid;
    int n0 = blockIdx.x * 32;                  // N divisible by 32
    {
        int row = tid >> 2, c4 = tid & 3;
        const float* src = (c4 < 2) ? (x    + (size_t)(n0 + row) * 8 + c4 * 4)
                                    : (agg1 + (size_t)(n0 + row) * 8 + (c4 - 2) * 4);
        *(float4*)&sN[row * 16 + c4 * 4] = *(const float4*)src;
    }
    float4 wl0 = *(const float4*)(W1l + f * 8);
    float4 wl1 = *(const float4*)(W1l + f * 8 + 4);
    float4 wr0 = *(const float4*)(W1r + f * 8);
    float4 wr1 = *(const float4*)(W1r + f * 8 + 4);
    float bb = b1[f];
    __syncthreads();
    float s = 0.f, s2 = 0.f;
    #pragma unroll 4
    for (int i = 0; i < 32; ++i) {
        float4 x0  = *(const float4*)&sN[i * 16];
        float4 x1v = *(const float4*)&sN[i * 16 + 4];
        float4 a0  = *(const float4*)&sN[i * 16 + 8];
        float4 a1  = *(const float4*)&sN[i * 16 + 12];
        float acc = bb;
        acc += a0.x*wl0.x + a0.y*wl0.y + a0.z*wl0.z + a0.w*wl0.w;
        acc += a1.x*wl1.x + a1.y*wl1.y + a1.z*wl1.z + a1.w*wl1.w;
        acc += x0.x*wr0.x + x0.y*wr0.y + x0.z*wr0.z + x0.w*wr0.w;
        acc += x1v.x*wr1.x + x1v.y*wr1.y + x1v.z*wr1.z + x1v.w*wr1.w;
        h1[(size_t)(n0 + i) * F + f] = acc;
        s += acc; s2 += acc * acc;
    }
    atomicAdd(&stats[f], s);
    atomicAdd(&stats[F + f], s2);
}

// fold BN into per-feature scale/shift
__global__ void k_bnfin(const float* __restrict__ stats, const float* __restrict__ gamma,
                        const float* __restrict__ beta, float* __restrict__ scsh) {
    int f = threadIdx.x;
    float mu  = stats[f] * (1.0f / N_NODES);
    float var = stats[F + f] * (1.0f / N_NODES) - mu * mu;
    float sc  = gamma[f] * rsqrtf(var + BN_EPS);
    scsh[f] = sc;
    scsh[F + f] = beta[f] - mu * sc;
}

// x1 = relu(scale*h1 + shift), in place
__global__ void k_bnrelu(float* __restrict__ h, const float* __restrict__ scsh) {
    size_t i = ((size_t)blockIdx.x * 256 + threadIdx.x) * 4;   // exact grid
    int f = (int)(i & (F - 1));
    float4 v = *(float4*)(h + i);
    v.x = fmaxf(0.f, v.x * scsh[f]     + scsh[F + f]);
    v.y = fmaxf(0.f, v.y * scsh[f + 1] + scsh[F + f + 1]);
    v.z = fmaxf(0.f, v.z * scsh[f + 2] + scsh[F + f + 2]);
    v.w = fmaxf(0.f, v.w * scsh[f + 3] + scsh[F + f + 3]);
    *(float4*)(h + i) = v;
}

// ---- layer 2 ---------------------------------------------------------------

// agg2[n][f] = mean over in-edges of x1[src][f]; 32 threads (float4) per node
__global__ void __launch_bounds__(256) k_agg2(
        const float* __restrict__ x1, const int* __restrict__ offs,
        const int* __restrict__ ssrc, float* __restrict__ agg2) {
    int t = threadIdx.x;
    int n = blockIdx.x * 8 + (t >> 5);
    int c4 = (t & 31) * 4;
    int s0 = offs[n], s1 = offs[n + 1];
    float4 acc = {0.f, 0.f, 0.f, 0.f};
    int j = s0;
    for (; j + 3 < s1; j += 4) {               // 4 gathers in flight
        int sa = ssrc[j], sb = ssrc[j + 1], sc = ssrc[j + 2], sd = ssrc[j + 3];
        float4 va = *(const float4*)(x1 + (size_t)sa * F + c4);
        float4 vb = *(const float4*)(x1 + (size_t)sb * F + c4);
        float4 vc = *(const float4*)(x1 + (size_t)sc * F + c4);
        float4 vd = *(const float4*)(x1 + (size_t)sd * F + c4);
        acc.x += (va.x + vb.x) + (vc.x + vd.x);
        acc.y += (va.y + vb.y) + (vc.y + vd.y);
        acc.z += (va.z + vb.z) + (vc.z + vd.z);
        acc.w += (va.w + vb.w) + (vc.w + vd.w);
    }
    for (; j < s1; ++j) {
        float4 v = *(const float4*)(x1 + (size_t)ssrc[j] * F + c4);
        acc.x += v.x; acc.y += v.y; acc.z += v.z; acc.w += v.w;
    }
    int dg = s1 - s0;
    float inv = 1.0f / (float)(dg > 1 ? dg : 1);
    acc.x *= inv; acc.y *= inv; acc.z *= inv; acc.w *= inv;
    *(float4*)(agg2 + (size_t)n * F + c4) = acc;
}

// h2 = agg2 @ W2l^T + b2 + x1 @ W2r^T, fused BN stats.
// Block 128: 32 node rows staged in LDS; thread = (f, f+64) x 16 nodes.
__global__ void __launch_bounds__(128) k_lin2(
        const float* __restrict__ agg2, const float* __restrict__ x1,
        const float4* __restrict__ Wl4, const float4* __restrict__ Wr4,
        const float* __restrict__ b2, float* __restrict__ h2,
        float* __restrict__ stats) {
    __shared__ float sA[32 * ROWF];
    __shared__ float sX[32 * ROWF];
    int tid = threadIdx.x;
    int f = tid & 63;
    int q = tid >> 6;                          // 0..1
    int nb = q * 16;
    int n0 = blockIdx.x * 32;                  // N divisible by 32

    // stage 32 rows of agg2 and x1 (coalesced float4)
    for (int e = tid; e < 2048; e += 128) {
        int m = e >> 10;                       // 0: agg2, 1: x1
        int r = (e >> 5) & 31, c4 = e & 31;
        const float* src = m ? x1 : agg2;
        float* dst = m ? sX : sA;
        float4 v = *(const float4*)(src + (size_t)(n0 + r) * F + c4 * 4);
        *(float4*)&dst[r * ROWF + c4 * 4] = v;
    }
    __syncthreads();

    float acc0[16], acc1[16];
    #pragma unroll
    for (int i = 0; i < 16; ++i) { acc0[i] = 0.f; acc1[i] = 0.f; }

    for (int k4 = 0; k4 < 32; ++k4) {
        float4 wl0 = Wl4[k4 * 128 + f];
        float4 wl1 = Wl4[k4 * 128 + f + 64];
        float4 wr0 = Wr4[k4 * 128 + f];
        float4 wr1 = Wr4[k4 * 128 + f + 64];
        #pragma unroll
        for (int i = 0; i < 16; ++i) {
            float4 a  = *(const float4*)&sA[(nb + i) * ROWF + k4 * 4];  // broadcast
            float4 xx = *(const float4*)&sX[(nb + i) * ROWF + k4 * 4];  // broadcast
            acc0[i] += a.x*wl0.x + a.y*wl0.y + a.z*wl0.z + a.w*wl0.w
                     + xx.x*wr0.x + xx.y*wr0.y + xx.z*wr0.z + xx.w*wr0.w;
            acc1[i] += a.x*wl1.x + a.y*wl1.y + a.z*wl1.z + a.w*wl1.w
                     + xx.x*wr1.x + xx.y*wr1.y + xx.z*wr1.z + xx.w*wr1.w;
        }
    }

    float bb0 = b2[f], bb1 = b2[f + 64];
    float ps0 = 0.f, ps0q = 0.f, ps1 = 0.f, ps1q = 0.f;
    #pragma unroll
    for (int i = 0; i < 16; ++i) {
        size_t n = (size_t)(n0 + nb + i);
        float v0 = acc0[i] + bb0, v1 = acc1[i] + bb1;
        h2[n * F + f] = v0;
        h2[n * F + f + 64] = v1;
        ps0 += v0; ps0q += v0 * v0;
        ps1 += v1; ps1q += v1 * v1;
    }

    // reduce the two quarters through LDS, then one atomic set per f
    __syncthreads();
    if (q == 1) {
        float4 t = {ps0, ps0q, ps1, ps1q};
        *(float4*)&sA[(tid - 64) * 4] = t;
    }
    __syncthreads();
    if (q == 0) {
        float4 t = *(const float4*)&sA[tid * 4];
        atomicAdd(&stats[f],          ps0  + t.x);
        atomicAdd(&stats[F + f],      ps0q + t.y);
        atomicAdd(&stats[f + 64],     ps1  + t.z);
        atomicAdd(&stats[F + f + 64], ps1q + t.w);
    }
}

// ---- pooling ---------------------------------------------------------------

// h = x1 + relu(scale2*h2 + shift2); per-graph running sums, flush on change
__global__ void k_pool(const float* __restrict__ x1, const float* __restrict__ h2,
                       const float* __restrict__ scsh2, const int* __restrict__ batch,
                       float* __restrict__ outacc) {
    int f = threadIdx.x;
    int n0 = blockIdx.x * 128;
    int n1 = min(n0 + 128, N_NODES);
    float sc = scsh2[f], sh = scsh2[F + f];
    float acc = 0.f;
    int curg = batch[n0];
    for (int n = n0; n < n1; ++n) {
        int g = batch[n];
        if (g != curg) {
            atomicAdd(&outacc[curg * F + f], acc);
            acc = 0.f; curg = g;
        }
        float v1 = x1[(size_t)n * F + f];
        float v2 = fmaxf(0.f, h2[(size_t)n * F + f] * sc + sh);
        acc += v1 + v2;
    }
    atomicAdd(&outacc[curg * F + f], acc);
}

__global__ void k_out(const float* __restrict__ outacc, const int* __restrict__ gstart,
                      float* __restrict__ out) {
    int i = blockIdx.x * 256 + threadIdx.x;
    if (i >= NUM_GRAPHS * F) return;
    int g = i >> 7;
    int c = gstart[g + 1] - gstart[g];
    out[i] = outacc[i] / (float)(c > 1 ? c : 1);
}

}  // namespace

extern "C" void kernel_launch(void* const* d_in, const int* in_sizes, int n_in,
                              void* d_out, int out_size, void* d_ws, size_t ws_size,
                              hipStream_t stream) {
    const float* x     = (const float*)d_in[0];
    const int*   ei    = (const int*)d_in[1];    // [2, E]: row0 = src, row1 = dst
    const int*   batch = (const int*)d_in[2];
    const float* W1l   = (const float*)d_in[3];
    const float* b1    = (const float*)d_in[4];
    const float* W1r   = (const float*)d_in[5];
    const float* g1    = (const float*)d_in[6];
    const float* be1   = (const float*)d_in[7];
    const float* W2l   = (const float*)d_in[8];
    const float* b2    = (const float*)d_in[9];
    const float* W2r   = (const float*)d_in[10];
    const float* g2    = (const float*)d_in[11];
    const float* be2   = (const float*)d_in[12];
    float* out = (float*)d_out;

    char* w = (char*)d_ws;
    size_t o = 0;
    auto alloc = [&](size_t bytes) {
        void* p = w + o;
        o += (bytes + 511) & ~(size_t)511;
        return p;
    };
    int*   deg    = (int*)alloc((size_t)N_NODES * 4);
    int*   offs   = (int*)alloc((size_t)(N_NODES + 1) * 4);
    int*   cursor = (int*)alloc((size_t)N_NODES * 4);
    int*   ssrc   = (int*)alloc((size_t)N_EDGES * 4);
    int*   bsums  = (int*)alloc(2048);
    int*   gstart = (int*)alloc((NUM_GRAPHS + 1) * 4);
    float* stats  = (float*)alloc(512 * 4);   // [s1,s1sq | s2,s2sq]
    float* scsh   = (float*)alloc(512 * 4);   // [sc1,sh1 | sc2,sh2]
    float* Wl4p   = (float*)alloc((size_t)F * F * 4);
    float* Wr4p   = (float*)alloc((size_t)F * F * 4);
    float* outacc = (float*)alloc((size_t)NUM_GRAPHS * F * 4);
    float* agg1   = (float*)alloc((size_t)N_NODES * 8 * 4);
    float* x1     = (float*)alloc((size_t)N_NODES * F * 4);   // h1 -> x1 in place
    float* agg2   = (float*)alloc((size_t)N_NODES * F * 4);
    float* h2     = (float*)alloc((size_t)N_NODES * F * 4);

    hipMemsetAsync(deg,    0, (size_t)N_NODES * 4, stream);
    hipMemsetAsync(cursor, 0, (size_t)N_NODES * 4, stream);
    hipMemsetAsync(stats,  0, 512 * 4, stream);
    hipMemsetAsync(outacc, 0, (size_t)NUM_GRAPHS * F * 4, stream);

    // CSR-by-dst edge sort + graph boundaries + weight repack
    k_hist   <<<(N_EDGES + 255) / 256, 256, 0, stream>>>(ei, deg);
    k_scan1  <<<SCAN_NB, 256, 0, stream>>>(deg, offs, bsums);
    k_scan2  <<<1, 512, 0, stream>>>(bsums);
    k_scan3  <<<SCAN_NB, 256, 0, stream>>>(offs, bsums);
    k_scatter<<<(N_EDGES + 255) / 256, 256, 0, stream>>>(ei, offs, cursor, ssrc);
    k_bound  <<<(N_NODES + 255) / 256, 256, 0, stream>>>(batch, gstart);
    k_pack   <<<64, 256, 0, stream>>>(W2l, Wl4p);
    k_pack   <<<64, 256, 0, stream>>>(W2r, Wr4p);

    // layer 1
    k_agg1  <<<(N_NODES + 255) / 256, 256, 0, stream>>>(x, offs, ssrc, agg1);
    k_lin1  <<<N_NODES / 32, 128, 0, stream>>>(x, agg1, W1l, b1, W1r, x1, stats);
    k_bnfin <<<1, 128, 0, stream>>>(stats, g1, be1, scsh);
    k_bnrelu<<<(N_NODES * F / 4) / 256, 256, 0, stream>>>(x1, scsh);

    // layer 2 (stats fused into k_lin2)
    k_agg2  <<<N_NODES / 8, 256, 0, stream>>>(x1, offs, ssrc, agg2);
    k_lin2  <<<N_NODES / 32, 128, 0, stream>>>(agg2, x1, (const float4*)Wl4p,
                                               (const float4*)Wr4p, b2, h2, stats + 256);
    k_bnfin <<<1, 128, 0, stream>>>(stats + 256, g2, be2, scsh + 256);

    // residual + pool
    k_pool<<<(N_NODES + 127) / 128, 128, 0, stream>>>(x1, h2, scsh + 256, batch, outacc);
    k_out <<<(NUM_GRAPHS * F + 255) / 256, 256, 0, stream>>>(outacc, gstart, out);
}

// Round 3
// 551.663 us; speedup vs baseline: 1.5787x; 1.2775x over previous
//
#include <hip/hip_runtime.h>
#include <cstdint>
#include <cstddef>

namespace {

constexpr int N_NODES = 100000;
constexpr int N_EDGES = 1600000;
constexpr int NUM_GRAPHS = 128;
constexpr int F = 128;
constexpr float BN_EPS = 1e-5f;
constexpr int SCAN_NB = (N_NODES + 255) / 256;   // 391

typedef float f32x4 __attribute__((ext_vector_type(4)));
typedef short s16x8 __attribute__((ext_vector_type(8)));
union B8 { uint4 u; s16x8 s; };

__device__ inline ushort f2bf(float x) {         // RNE fp32 -> bf16
    uint u = __float_as_uint(x);
    u += 0x7fffu + ((u >> 16) & 1u);
    return (ushort)(u >> 16);
}
__device__ inline float bf2f(ushort s) { return __uint_as_float(((uint)s) << 16); }
__device__ inline uint pack2(float lo, float hi) {
    return (uint)f2bf(lo) | ((uint)f2bf(hi) << 16);
}
__device__ inline float bflo(uint u) { return __uint_as_float(u << 16); }
__device__ inline float bfhi(uint u) { return __uint_as_float(u & 0xffff0000u); }

// ---- edge sort (CSR by dst) ------------------------------------------------

__global__ void k_hist(const int* __restrict__ ei, int* __restrict__ deg) {
    int e = blockIdx.x * 256 + threadIdx.x;
    if (e < N_EDGES) atomicAdd(&deg[ei[N_EDGES + e]], 1);
}

__global__ void k_scan1(const int* __restrict__ deg, int* __restrict__ offs,
                        int* __restrict__ bsums) {
    __shared__ int tmp[256];
    int i = blockIdx.x * 256 + threadIdx.x;
    int v = (i < N_NODES) ? deg[i] : 0;
    tmp[threadIdx.x] = v;
    __syncthreads();
    #pragma unroll
    for (int d = 1; d < 256; d <<= 1) {
        int t = (threadIdx.x >= d) ? tmp[threadIdx.x - d] : 0;
        __syncthreads();
        tmp[threadIdx.x] += t;
        __syncthreads();
    }
    if (i < N_NODES) offs[i] = tmp[threadIdx.x] - v;
    if (threadIdx.x == 255) bsums[blockIdx.x] = tmp[255];
}

__global__ void k_scan2(int* __restrict__ bsums) {
    __shared__ int tmp[512];
    int i = threadIdx.x;
    int v = (i < SCAN_NB) ? bsums[i] : 0;
    tmp[i] = v;
    __syncthreads();
    #pragma unroll
    for (int d = 1; d < 512; d <<= 1) {
        int t = (i >= d) ? tmp[i - d] : 0;
        __syncthreads();
        tmp[i] += t;
        __syncthreads();
    }
    if (i < SCAN_NB) bsums[i] = tmp[i] - v;
}

__global__ void k_scan3(int* __restrict__ offs, const int* __restrict__ bsums) {
    int i = blockIdx.x * 256 + threadIdx.x;
    if (i < N_NODES) offs[i] += bsums[blockIdx.x];
    if (i == 0) offs[N_NODES] = N_EDGES;
}

__global__ void k_scatter(const int* __restrict__ ei, const int* __restrict__ offs,
                          int* __restrict__ cursor, int* __restrict__ ssrc) {
    int e = blockIdx.x * 256 + threadIdx.x;
    if (e >= N_EDGES) return;
    int d = ei[N_EDGES + e];
    int p = offs[d] + atomicAdd(&cursor[d], 1);
    ssrc[p] = ei[e];
}

// ---- graph segment boundaries (batch is sorted) ----------------------------

__global__ void k_bound(const int* __restrict__ batch, int* __restrict__ gstart) {
    int i = blockIdx.x * 256 + threadIdx.x;
    if (i >= N_NODES) return;
    int b = batch[i];
    if (i == 0) {
        for (int g = 0; g <= b; ++g) gstart[g] = 0;
    } else {
        int p = batch[i - 1];
        if (p != b) for (int g = p + 1; g <= b; ++g) gstart[g] = i;
    }
    if (i == N_NODES - 1) {
        for (int g = b + 1; g <= NUM_GRAPHS; ++g) gstart[g] = N_NODES;
    }
}

// ---- weight pack: Wcat[f][0:128]=W2l[f][:], Wcat[f][128:256]=W2r[f][:], bf16

__global__ void k_packbf(const float* __restrict__ Wl, const float* __restrict__ Wr,
                         ushort* __restrict__ Wcat) {
    int i = blockIdx.x * 256 + threadIdx.x;    // 16384 exact
    int f = i >> 7, k = i & 127;
    Wcat[f * 256 + k]       = f2bf(Wl[i]);
    Wcat[f * 256 + 128 + k] = f2bf(Wr[i]);
}

// ---- layer 1 (fp32) --------------------------------------------------------

__global__ void k_agg1(const float* __restrict__ x, const int* __restrict__ offs,
                       const int* __restrict__ ssrc, float* __restrict__ agg1) {
    int n = blockIdx.x * 256 + threadIdx.x;
    if (n >= N_NODES) return;
    int s0 = offs[n], s1 = offs[n + 1];
    float a0=0,a1=0,a2=0,a3=0,a4=0,a5=0,a6=0,a7=0;
    for (int j = s0; j < s1; ++j) {
        const float4* xp = (const float4*)(x + (size_t)ssrc[j] * 8);
        float4 b0 = xp[0], b1 = xp[1];
        a0+=b0.x; a1+=b0.y; a2+=b0.z; a3+=b0.w;
        a4+=b1.x; a5+=b1.y; a6+=b1.z; a7+=b1.w;
    }
    int dg = s1 - s0;
    float inv = 1.0f / (float)(dg > 1 ? dg : 1);
    float4 o0 = {a0*inv, a1*inv, a2*inv, a3*inv};
    float4 o1 = {a4*inv, a5*inv, a6*inv, a7*inv};
    float4* op = (float4*)(agg1 + (size_t)n * 8);
    op[0] = o0; op[1] = o1;
}

__global__ void __launch_bounds__(128) k_lin1(
        const float* __restrict__ x, const float* __restrict__ agg1,
        const float* __restrict__ W1l, const float* __restrict__ b1,
        const float* __restrict__ W1r, float* __restrict__ h1,
        float* __restrict__ stats) {
    __shared__ float sN[32 * 16];              // per node: [x 0..7 | agg1 8..15]
    int tid = threadIdx.x, f = tid;
    int n0 = blockIdx.x * 32;                  // N divisible by 32
    {
        int row = tid >> 2, c4 = tid & 3;
        const float* src = (c4 < 2) ? (x    + (size_t)(n0 + row) * 8 + c4 * 4)
                                    : (agg1 + (size_t)(n0 + row) * 8 + (c4 - 2) * 4);
        *(float4*)&sN[row * 16 + c4 * 4] = *(const float4*)src;
    }
    float4 wl0 = *(const float4*)(W1l + f * 8);
    float4 wl1 = *(const float4*)(W1l + f * 8 + 4);
    float4 wr0 = *(const float4*)(W1r + f * 8);
    float4 wr1 = *(const float4*)(W1r + f * 8 + 4);
    float bb = b1[f];
    __syncthreads();
    float s = 0.f, s2 = 0.f;
    #pragma unroll 4
    for (int i = 0; i < 32; ++i) {
        float4 x0  = *(const float4*)&sN[i * 16];
        float4 x1v = *(const float4*)&sN[i * 16 + 4];
        float4 a0  = *(const float4*)&sN[i * 16 + 8];
        float4 a1  = *(const float4*)&sN[i * 16 + 12];
        float acc = bb;
        acc += a0.x*wl0.x + a0.y*wl0.y + a0.z*wl0.z + a0.w*wl0.w;
        acc += a1.x*wl1.x + a1.y*wl1.y + a1.z*wl1.z + a1.w*wl1.w;
        acc += x0.x*wr0.x + x0.y*wr0.y + x0.z*wr0.z + x0.w*wr0.w;
        acc += x1v.x*wr1.x + x1v.y*wr1.y + x1v.z*wr1.z + x1v.w*wr1.w;
        h1[(size_t)(n0 + i) * F + f] = acc;
        s += acc; s2 += acc * acc;
    }
    atomicAdd(&stats[f], s);
    atomicAdd(&stats[F + f], s2);
}

__global__ void k_bnfin(const float* __restrict__ stats, const float* __restrict__ gamma,
                        const float* __restrict__ beta, float* __restrict__ scsh) {
    int f = threadIdx.x;
    float mu  = stats[f] * (1.0f / N_NODES);
    float var = stats[F + f] * (1.0f / N_NODES) - mu * mu;
    float sc  = gamma[f] * rsqrtf(var + BN_EPS);
    scsh[f] = sc;
    scsh[F + f] = beta[f] - mu * sc;
}

// x1bf = bf16(relu(scale*h1 + shift))
__global__ void k_bnrelu(const float* __restrict__ h, const float* __restrict__ scsh,
                         ushort* __restrict__ x1bf) {
    int i = blockIdx.x * 256 + threadIdx.x;      // N*128/8 = 1.6M exact
    int base = i * 8;
    int f = base & (F - 1);
    float4 sc0 = *(const float4*)(scsh + f);
    float4 sc1 = *(const float4*)(scsh + f + 4);
    float4 sh0 = *(const float4*)(scsh + F + f);
    float4 sh1 = *(const float4*)(scsh + F + f + 4);
    float4 a = *(const float4*)(h + base);
    float4 b = *(const float4*)(h + base + 4);
    float v0 = fmaxf(0.f, a.x*sc0.x + sh0.x);
    float v1 = fmaxf(0.f, a.y*sc0.y + sh0.y);
    float v2 = fmaxf(0.f, a.z*sc0.z + sh0.z);
    float v3 = fmaxf(0.f, a.w*sc0.w + sh0.w);
    float v4 = fmaxf(0.f, b.x*sc1.x + sh1.x);
    float v5 = fmaxf(0.f, b.y*sc1.y + sh1.y);
    float v6 = fmaxf(0.f, b.z*sc1.z + sh1.z);
    float v7 = fmaxf(0.f, b.w*sc1.w + sh1.w);
    uint4 o = {pack2(v0,v1), pack2(v2,v3), pack2(v4,v5), pack2(v6,v7)};
    *(uint4*)(x1bf + base) = o;
}

// ---- layer 2 ---------------------------------------------------------------

// agg2bf[n][f] = bf16(mean over in-edges of x1bf[src][f]); 16 threads x 16B/node
__global__ void __launch_bounds__(256) k_agg2(
        const ushort* __restrict__ x1bf, const int* __restrict__ offs,
        const int* __restrict__ ssrc, ushort* __restrict__ agg2bf) {
    int t = threadIdx.x;
    int n = blockIdx.x * 16 + (t >> 4);
    int c8 = (t & 15) * 8;
    int s0 = offs[n], s1 = offs[n + 1];
    float acc[8] = {0,0,0,0,0,0,0,0};
    int j = s0;
    for (; j + 3 < s1; j += 4) {               // 4 gathers in flight
        int sa = ssrc[j], sb = ssrc[j+1], sc = ssrc[j+2], sd = ssrc[j+3];
        uint4 va = *(const uint4*)(x1bf + (size_t)sa * F + c8);
        uint4 vb = *(const uint4*)(x1bf + (size_t)sb * F + c8);
        uint4 vc = *(const uint4*)(x1bf + (size_t)sc * F + c8);
        uint4 vd = *(const uint4*)(x1bf + (size_t)sd * F + c8);
        acc[0] += (bflo(va.x)+bflo(vb.x)) + (bflo(vc.x)+bflo(vd.x));
        acc[1] += (bfhi(va.x)+bfhi(vb.x)) + (bfhi(vc.x)+bfhi(vd.x));
        acc[2] += (bflo(va.y)+bflo(vb.y)) + (bflo(vc.y)+bflo(vd.y));
        acc[3] += (bfhi(va.y)+bfhi(vb.y)) + (bfhi(vc.y)+bfhi(vd.y));
        acc[4] += (bflo(va.z)+bflo(vb.z)) + (bflo(vc.z)+bflo(vd.z));
        acc[5] += (bfhi(va.z)+bfhi(vb.z)) + (bfhi(vc.z)+bfhi(vd.z));
        acc[6] += (bflo(va.w)+bflo(vb.w)) + (bflo(vc.w)+bflo(vd.w));
        acc[7] += (bfhi(va.w)+bfhi(vb.w)) + (bfhi(vc.w)+bfhi(vd.w));
    }
    for (; j < s1; ++j) {
        uint4 v = *(const uint4*)(x1bf + (size_t)ssrc[j] * F + c8);
        acc[0] += bflo(v.x); acc[1] += bfhi(v.x);
        acc[2] += bflo(v.y); acc[3] += bfhi(v.y);
        acc[4] += bflo(v.z); acc[5] += bfhi(v.z);
        acc[6] += bflo(v.w); acc[7] += bfhi(v.w);
    }
    int dg = s1 - s0;
    float inv = 1.0f / (float)(dg > 1 ? dg : 1);
    uint4 o = {pack2(acc[0]*inv, acc[1]*inv), pack2(acc[2]*inv, acc[3]*inv),
               pack2(acc[4]*inv, acc[5]*inv), pack2(acc[6]*inv, acc[7]*inv)};
    *(uint4*)(agg2bf + (size_t)n * F + c8) = o;
}

// h2 = agg2 @ W2l^T + b2 + x1 @ W2r^T via bf16 MFMA; BN stats fused.
// Block 256 = 4 waves; wave = 32 nodes (2 m-tiles of 16); K = 256 (8 k-steps).
__global__ void __launch_bounds__(256) k_lin2(
        const ushort* __restrict__ agg2bf, const ushort* __restrict__ x1bf,
        const ushort* __restrict__ Wcat, const float* __restrict__ b2,
        ushort* __restrict__ h2bf, float* __restrict__ stats) {
    __shared__ ushort sOut[128 * 136];         // 128x128 bf16 tile, stride 136
    __shared__ float sred[256];
    int tid = threadIdx.x;
    int wave = tid >> 6, lane = tid & 63;
    int quad = lane >> 4, l16 = lane & 15;
    int n0 = blockIdx.x * 128 + wave * 32;

    // preload A fragments: a[mt][ks], lane holds A[node = n0+mt*16+l16][k0..k0+7]
    s16x8 a[2][8];
    #pragma unroll
    for (int mt = 0; mt < 2; ++mt) {
        int node = n0 + mt * 16 + l16;
        if (node >= N_NODES) node = N_NODES - 1;   // clamp; stores masked below
        #pragma unroll
        for (int ks = 0; ks < 8; ++ks) {
            const ushort* src = (ks < 4) ? agg2bf : x1bf;
            B8 tm;
            tm.u = *(const uint4*)(src + (size_t)node * F + (ks & 3) * 32 + quad * 8);
            a[mt][ks] = tm.s;
        }
    }

    #pragma unroll
    for (int nt = 0; nt < 8; ++nt) {
        int fb = nt * 16 + l16;
        s16x8 b[8];
        #pragma unroll
        for (int ks = 0; ks < 8; ++ks) {
            B8 tm;
            tm.u = *(const uint4*)(Wcat + fb * 256 + ks * 32 + quad * 8);
            b[ks] = tm.s;
        }
        f32x4 acc0 = {0.f, 0.f, 0.f, 0.f};
        f32x4 acc1 = {0.f, 0.f, 0.f, 0.f};
        #pragma unroll
        for (int ks = 0; ks < 8; ++ks) {
            acc0 = __builtin_amdgcn_mfma_f32_16x16x32_bf16(a[0][ks], b[ks], acc0, 0, 0, 0);
            acc1 = __builtin_amdgcn_mfma_f32_16x16x32_bf16(a[1][ks], b[ks], acc1, 0, 0, 0);
        }
        float bb = b2[fb];
        #pragma unroll
        for (int r = 0; r < 4; ++r) {
            int row0 = wave * 32 + quad * 4 + r;          // mt = 0
            sOut[row0 * 136 + fb]        = f2bf(acc0[r] + bb);
            sOut[(row0 + 16) * 136 + fb] = f2bf(acc1[r] + bb);
        }
    }
    __syncthreads();

    // coalesced write of the 128x128 bf16 tile
    #pragma unroll
    for (int p = 0; p < 8; ++p) {
        int row = p * 16 + (tid >> 4);
        int node = blockIdx.x * 128 + row;
        if (node < N_NODES) {
            int c0 = (tid & 15) * 8;
            uint4 v = *(const uint4*)&sOut[row * 136 + c0];
            *(uint4*)(h2bf + (size_t)node * F + c0) = v;
        }
    }

    // fused BN stats from the staged tile
    int f = tid & 127, half = tid >> 7;
    float s = 0.f, s2 = 0.f;
    for (int r = half * 64; r < half * 64 + 64; ++r) {
        int node = blockIdx.x * 128 + r;
        if (node >= N_NODES) break;
        float v = bf2f(sOut[r * 136 + f]);
        s += v; s2 += v * v;
    }
    if (half) { sred[f] = s; sred[128 + f] = s2; }
    __syncthreads();
    if (!half) {
        s += sred[f]; s2 += sred[128 + f];
        atomicAdd(&stats[f], s);
        atomicAdd(&stats[F + f], s2);
    }
}

// ---- pooling ---------------------------------------------------------------

__global__ void k_pool(const ushort* __restrict__ x1bf, const ushort* __restrict__ h2bf,
                       const float* __restrict__ scsh2, const int* __restrict__ batch,
                       float* __restrict__ outacc) {
    int f = threadIdx.x;
    int n0 = blockIdx.x * 128;
    int n1 = min(n0 + 128, N_NODES);
    float sc = scsh2[f], sh = scsh2[F + f];
    float acc = 0.f;
    int curg = batch[n0];
    for (int n = n0; n < n1; ++n) {
        int g = batch[n];
        if (g != curg) {
            atomicAdd(&outacc[curg * F + f], acc);
            acc = 0.f; curg = g;
        }
        float v1 = bf2f(x1bf[(size_t)n * F + f]);
        float v2 = fmaxf(0.f, bf2f(h2bf[(size_t)n * F + f]) * sc + sh);
        acc += v1 + v2;
    }
    atomicAdd(&outacc[curg * F + f], acc);
}

__global__ void k_out(const float* __restrict__ outacc, const int* __restrict__ gstart,
                      float* __restrict__ out) {
    int i = blockIdx.x * 256 + threadIdx.x;
    if (i >= NUM_GRAPHS * F) return;
    int g = i >> 7;
    int c = gstart[g + 1] - gstart[g];
    out[i] = outacc[i] / (float)(c > 1 ? c : 1);
}

}  // namespace

extern "C" void kernel_launch(void* const* d_in, const int* in_sizes, int n_in,
                              void* d_out, int out_size, void* d_ws, size_t ws_size,
                              hipStream_t stream) {
    const float* x     = (const float*)d_in[0];
    const int*   ei    = (const int*)d_in[1];    // [2, E]: row0 = src, row1 = dst
    const int*   batch = (const int*)d_in[2];
    const float* W1l   = (const float*)d_in[3];
    const float* b1    = (const float*)d_in[4];
    const float* W1r   = (const float*)d_in[5];
    const float* g1    = (const float*)d_in[6];
    const float* be1   = (const float*)d_in[7];
    const float* W2l   = (const float*)d_in[8];
    const float* b2    = (const float*)d_in[9];
    const float* W2r   = (const float*)d_in[10];
    const float* g2    = (const float*)d_in[11];
    const float* be2   = (const float*)d_in[12];
    float* out = (float*)d_out;

    char* w = (char*)d_ws;
    size_t o = 0;
    auto alloc = [&](size_t bytes) {
        void* p = w + o;
        o += (bytes + 511) & ~(size_t)511;
        return p;
    };
    int*    deg    = (int*)alloc((size_t)N_NODES * 4);
    int*    offs   = (int*)alloc((size_t)(N_NODES + 1) * 4);
    int*    cursor = (int*)alloc((size_t)N_NODES * 4);
    int*    ssrc   = (int*)alloc((size_t)N_EDGES * 4);
    int*    bsums  = (int*)alloc(2048);
    int*    gstart = (int*)alloc((NUM_GRAPHS + 1) * 4);
    float*  stats  = (float*)alloc(512 * 4);   // [s1,s1sq | s2,s2sq]
    float*  scsh   = (float*)alloc(512 * 4);   // [sc1,sh1 | sc2,sh2]
    ushort* Wcat   = (ushort*)alloc((size_t)F * 256 * 2);
    float*  outacc = (float*)alloc((size_t)NUM_GRAPHS * F * 4);
    float*  agg1   = (float*)alloc((size_t)N_NODES * 8 * 4);
    float*  h1     = (float*)alloc((size_t)N_NODES * F * 4);
    ushort* x1bf   = (ushort*)alloc((size_t)N_NODES * F * 2);
    ushort* agg2bf = (ushort*)alloc((size_t)N_NODES * F * 2);
    ushort* h2bf   = (ushort*)alloc((size_t)N_NODES * F * 2);

    hipMemsetAsync(deg,    0, (size_t)N_NODES * 4, stream);
    hipMemsetAsync(cursor, 0, (size_t)N_NODES * 4, stream);
    hipMemsetAsync(stats,  0, 512 * 4, stream);
    hipMemsetAsync(outacc, 0, (size_t)NUM_GRAPHS * F * 4, stream);

    // CSR-by-dst edge sort + graph boundaries + bf16 weight pack
    k_hist   <<<(N_EDGES + 255) / 256, 256, 0, stream>>>(ei, deg);
    k_scan1  <<<SCAN_NB, 256, 0, stream>>>(deg, offs, bsums);
    k_scan2  <<<1, 512, 0, stream>>>(bsums);
    k_scan3  <<<SCAN_NB, 256, 0, stream>>>(offs, bsums);
    k_scatter<<<(N_EDGES + 255) / 256, 256, 0, stream>>>(ei, offs, cursor, ssrc);
    k_bound  <<<(N_NODES + 255) / 256, 256, 0, stream>>>(batch, gstart);
    k_packbf <<<64, 256, 0, stream>>>(W2l, W2r, Wcat);

    // layer 1 (fp32)
    k_agg1  <<<(N_NODES + 255) / 256, 256, 0, stream>>>(x, offs, ssrc, agg1);
    k_lin1  <<<N_NODES / 32, 128, 0, stream>>>(x, agg1, W1l, b1, W1r, h1, stats);
    k_bnfin <<<1, 128, 0, stream>>>(stats, g1, be1, scsh);
    k_bnrelu<<<(N_NODES * F / 8) / 256, 256, 0, stream>>>(h1, scsh, x1bf);

    // layer 2 (bf16 + MFMA; stats fused into k_lin2)
    k_agg2  <<<N_NODES / 16, 256, 0, stream>>>(x1bf, offs, ssrc, agg2bf);
    k_lin2  <<<(N_NODES + 127) / 128, 256, 0, stream>>>(agg2bf, x1bf, Wcat, b2,
                                                        h2bf, stats + 256);
    k_bnfin <<<1, 128, 0, stream>>>(stats + 256, g2, be2, scsh + 256);

    // residual + pool
    k_pool<<<(N_NODES + 127) / 128, 128, 0, stream>>>(x1bf, h2bf, scsh + 256, batch, outacc);
    k_out <<<(NUM_GRAPHS * F + 255) / 256, 256, 0, stream>>>(outacc, gstart, out);
}

// Round 4
// 521.414 us; speedup vs baseline: 1.6703x; 1.0580x over previous
//
#include <hip/hip_runtime.h>
#include <cstdint>
#include <cstddef>

namespace {

constexpr int N_NODES = 100000;
constexpr int N_EDGES = 1600000;
constexpr int NUM_GRAPHS = 128;
constexpr int F = 128;
constexpr float BN_EPS = 1e-5f;
constexpr int SCAN_NB = (N_NODES + 255) / 256;   // 391

// bucket sort params: 196 buckets x 512 nodes; 200 chunks x 8000 edges
constexpr int W_BUCK = 512;
constexpr int NBUCK = (N_NODES + W_BUCK - 1) / W_BUCK;  // 196
constexpr int CB = 200;
constexpr int CHUNK = N_EDGES / CB;                      // 8000

typedef float f32x4 __attribute__((ext_vector_type(4)));
typedef short s16x8 __attribute__((ext_vector_type(8)));
union B8 { uint4 u; s16x8 s; };

__device__ inline ushort f2bf(float x) {         // RNE fp32 -> bf16
    uint u = __float_as_uint(x);
    u += 0x7fffu + ((u >> 16) & 1u);
    return (ushort)(u >> 16);
}
__device__ inline float bf2f(ushort s) { return __uint_as_float(((uint)s) << 16); }
__device__ inline uint pack2(float lo, float hi) {
    return (uint)f2bf(lo) | ((uint)f2bf(hi) << 16);
}
__device__ inline float bflo(uint u) { return __uint_as_float(u << 16); }
__device__ inline float bfhi(uint u) { return __uint_as_float(u & 0xffff0000u); }

// ---- CSR-by-dst via 2-level bucket sort (line-local writes) -----------------

// per-chunk bucket histogram + global node degree
__global__ void __launch_bounds__(256) k_histA(const int* __restrict__ ei,
                                               int* __restrict__ deg,
                                               int* __restrict__ gcount) {
    __shared__ int bins[NBUCK];
    int t = threadIdx.x;
    for (int i = t; i < NBUCK; i += 256) bins[i] = 0;
    __syncthreads();
    int e0 = blockIdx.x * CHUNK;
    for (int i = t; i < CHUNK; i += 256) {
        int d = ei[N_EDGES + e0 + i];
        atomicAdd(&deg[d], 1);
        atomicAdd(&bins[d >> 9], 1);
    }
    __syncthreads();
    for (int i = t; i < NBUCK; i += 256) gcount[i * CB + blockIdx.x] = bins[i];
}

// single-block in-place exclusive scan of gcount (NBUCK*CB = 39200 ints)
__global__ void __launch_bounds__(1024) k_scanG(int* __restrict__ g, int n) {
    __shared__ int ts[1024];
    int t = threadIdx.x;
    int per = (n + 1023) / 1024;
    int lo = t * per, hi = min(lo + per, n);
    int s = 0;
    for (int i = lo; i < hi; ++i) s += g[i];
    ts[t] = s;
    __syncthreads();
    #pragma unroll
    for (int d = 1; d < 1024; d <<= 1) {
        int v = (t >= d) ? ts[t - d] : 0;
        __syncthreads();
        ts[t] += v;
        __syncthreads();
    }
    int run = ts[t] - s;
    for (int i = lo; i < hi; ++i) {
        int v = g[i];
        g[i] = run;
        run += v;
    }
}

// partition edges into bucket runs; packed u32 = (src<<9)|(dst&511)
__global__ void __launch_bounds__(256) k_part(const int* __restrict__ ei,
                                              const int* __restrict__ goffs,
                                              uint* __restrict__ epk) {
    __shared__ int cur[NBUCK];
    int t = threadIdx.x;
    for (int i = t; i < NBUCK; i += 256) cur[i] = goffs[i * CB + blockIdx.x];
    __syncthreads();
    int e0 = blockIdx.x * CHUNK;
    for (int i = t; i < CHUNK; i += 256) {
        int d = ei[N_EDGES + e0 + i];
        int s = ei[e0 + i];
        int p = atomicAdd(&cur[d >> 9], 1);
        epk[p] = ((uint)s << 9) | (uint)(d & 511);
    }
}

// per-bucket counting sort into final CSR positions (L2-local scatter)
__global__ void __launch_bounds__(512) k_rank(const uint* __restrict__ epk,
                                              const int* __restrict__ goffs,
                                              const int* __restrict__ offs,
                                              int* __restrict__ ssrc) {
    __shared__ int cur[W_BUCK];
    int b = blockIdx.x, t = threadIdx.x;
    int node = b * W_BUCK + t;
    cur[t] = (node < N_NODES) ? offs[node] : 0;
    __syncthreads();
    int s0 = goffs[b * CB];
    int s1 = (b + 1 < NBUCK) ? goffs[(b + 1) * CB] : N_EDGES;
    for (int i = s0 + t; i < s1; i += 512) {
        uint u = epk[i];
        int p = atomicAdd(&cur[u & 511u], 1);
        ssrc[p] = (int)(u >> 9);
    }
}

// ---- node-offset scans ------------------------------------------------------

__global__ void k_scan1(const int* __restrict__ deg, int* __restrict__ offs,
                        int* __restrict__ bsums) {
    __shared__ int tmp[256];
    int i = blockIdx.x * 256 + threadIdx.x;
    int v = (i < N_NODES) ? deg[i] : 0;
    tmp[threadIdx.x] = v;
    __syncthreads();
    #pragma unroll
    for (int d = 1; d < 256; d <<= 1) {
        int t = (threadIdx.x >= d) ? tmp[threadIdx.x - d] : 0;
        __syncthreads();
        tmp[threadIdx.x] += t;
        __syncthreads();
    }
    if (i < N_NODES) offs[i] = tmp[threadIdx.x] - v;
    if (threadIdx.x == 255) bsums[blockIdx.x] = tmp[255];
}

__global__ void k_scan2(int* __restrict__ bsums) {
    __shared__ int tmp[512];
    int i = threadIdx.x;
    int v = (i < SCAN_NB) ? bsums[i] : 0;
    tmp[i] = v;
    __syncthreads();
    #pragma unroll
    for (int d = 1; d < 512; d <<= 1) {
        int t = (i >= d) ? tmp[i - d] : 0;
        __syncthreads();
        tmp[i] += t;
        __syncthreads();
    }
    if (i < SCAN_NB) bsums[i] = tmp[i] - v;
}

__global__ void k_scan3(int* __restrict__ offs, const int* __restrict__ bsums) {
    int i = blockIdx.x * 256 + threadIdx.x;
    if (i < N_NODES) offs[i] += bsums[blockIdx.x];
    if (i == 0) offs[N_NODES] = N_EDGES;
}

// ---- graph segment boundaries (batch is sorted) ----------------------------

__global__ void k_bound(const int* __restrict__ batch, int* __restrict__ gstart) {
    int i = blockIdx.x * 256 + threadIdx.x;
    if (i >= N_NODES) return;
    int b = batch[i];
    if (i == 0) {
        for (int g = 0; g <= b; ++g) gstart[g] = 0;
    } else {
        int p = batch[i - 1];
        if (p != b) for (int g = p + 1; g <= b; ++g) gstart[g] = i;
    }
    if (i == N_NODES - 1) {
        for (int g = b + 1; g <= NUM_GRAPHS; ++g) gstart[g] = N_NODES;
    }
}

// ---- weight pack: Wcat[f][0:128]=W2l[f][:], Wcat[f][128:256]=W2r[f][:], bf16

__global__ void k_packbf(const float* __restrict__ Wl, const float* __restrict__ Wr,
                         ushort* __restrict__ Wcat) {
    int i = blockIdx.x * 256 + threadIdx.x;    // 16384 exact
    int f = i >> 7, k = i & 127;
    Wcat[f * 256 + k]       = f2bf(Wl[i]);
    Wcat[f * 256 + 128 + k] = f2bf(Wr[i]);
}

// ---- layer 1 ---------------------------------------------------------------

__global__ void k_agg1(const float* __restrict__ x, const int* __restrict__ offs,
                       const int* __restrict__ ssrc, float* __restrict__ agg1) {
    int n = blockIdx.x * 256 + threadIdx.x;
    if (n >= N_NODES) return;
    int s0 = offs[n], s1 = offs[n + 1];
    float a0=0,a1=0,a2=0,a3=0,a4=0,a5=0,a6=0,a7=0;
    for (int j = s0; j < s1; ++j) {
        const float4* xp = (const float4*)(x + (size_t)ssrc[j] * 8);
        float4 b0 = xp[0], b1 = xp[1];
        a0+=b0.x; a1+=b0.y; a2+=b0.z; a3+=b0.w;
        a4+=b1.x; a5+=b1.y; a6+=b1.z; a7+=b1.w;
    }
    int dg = s1 - s0;
    float inv = 1.0f / (float)(dg > 1 ? dg : 1);
    float4 o0 = {a0*inv, a1*inv, a2*inv, a3*inv};
    float4 o1 = {a4*inv, a5*inv, a6*inv, a7*inv};
    float4* op = (float4*)(agg1 + (size_t)n * 8);
    op[0] = o0; op[1] = o1;
}

// h1bf = bf16(agg1 @ W1l^T + b1 + x @ W1r^T); fp32 BN stats fused
__global__ void __launch_bounds__(128) k_lin1(
        const float* __restrict__ x, const float* __restrict__ agg1,
        const float* __restrict__ W1l, const float* __restrict__ b1,
        const float* __restrict__ W1r, ushort* __restrict__ h1bf,
        float* __restrict__ stats) {
    __shared__ float sN[32 * 16];              // per node: [x 0..7 | agg1 8..15]
    int tid = threadIdx.x, f = tid;
    int n0 = blockIdx.x * 32;                  // N divisible by 32
    {
        int row = tid >> 2, c4 = tid & 3;
        const float* src = (c4 < 2) ? (x    + (size_t)(n0 + row) * 8 + c4 * 4)
                                    : (agg1 + (size_t)(n0 + row) * 8 + (c4 - 2) * 4);
        *(float4*)&sN[row * 16 + c4 * 4] = *(const float4*)src;
    }
    float4 wl0 = *(const float4*)(W1l + f * 8);
    float4 wl1 = *(const float4*)(W1l + f * 8 + 4);
    float4 wr0 = *(const float4*)(W1r + f * 8);
    float4 wr1 = *(const float4*)(W1r + f * 8 + 4);
    float bb = b1[f];
    __syncthreads();
    float s = 0.f, s2 = 0.f;
    #pragma unroll 4
    for (int i = 0; i < 32; ++i) {
        float4 x0  = *(const float4*)&sN[i * 16];
        float4 x1v = *(const float4*)&sN[i * 16 + 4];
        float4 a0  = *(const float4*)&sN[i * 16 + 8];
        float4 a1  = *(const float4*)&sN[i * 16 + 12];
        float acc = bb;
        acc += a0.x*wl0.x + a0.y*wl0.y + a0.z*wl0.z + a0.w*wl0.w;
        acc += a1.x*wl1.x + a1.y*wl1.y + a1.z*wl1.z + a1.w*wl1.w;
        acc += x0.x*wr0.x + x0.y*wr0.y + x0.z*wr0.z + x0.w*wr0.w;
        acc += x1v.x*wr1.x + x1v.y*wr1.y + x1v.z*wr1.z + x1v.w*wr1.w;
        h1bf[(size_t)(n0 + i) * F + f] = f2bf(acc);
        s += acc; s2 += acc * acc;
    }
    atomicAdd(&stats[f], s);
    atomicAdd(&stats[F + f], s2);
}

__global__ void k_bnfin(const float* __restrict__ stats, const float* __restrict__ gamma,
                        const float* __restrict__ beta, float* __restrict__ scsh) {
    int f = threadIdx.x;
    float mu  = stats[f] * (1.0f / N_NODES);
    float var = stats[F + f] * (1.0f / N_NODES) - mu * mu;
    float sc  = gamma[f] * rsqrtf(var + BN_EPS);
    scsh[f] = sc;
    scsh[F + f] = beta[f] - mu * sc;
}

// x1bf = bf16(relu(scale*h1 + shift))
__global__ void k_bnrelu(const ushort* __restrict__ h, const float* __restrict__ scsh,
                         ushort* __restrict__ x1bf) {
    int i = blockIdx.x * 256 + threadIdx.x;      // N*128/8 = 1.6M exact
    int base = i * 8;
    int f = base & (F - 1);
    float4 sc0 = *(const float4*)(scsh + f);
    float4 sc1 = *(const float4*)(scsh + f + 4);
    float4 sh0 = *(const float4*)(scsh + F + f);
    float4 sh1 = *(const float4*)(scsh + F + f + 4);
    uint4 hv = *(const uint4*)(h + base);
    float v0 = fmaxf(0.f, bflo(hv.x)*sc0.x + sh0.x);
    float v1 = fmaxf(0.f, bfhi(hv.x)*sc0.y + sh0.y);
    float v2 = fmaxf(0.f, bflo(hv.y)*sc0.z + sh0.z);
    float v3 = fmaxf(0.f, bfhi(hv.y)*sc0.w + sh0.w);
    float v4 = fmaxf(0.f, bflo(hv.z)*sc1.x + sh1.x);
    float v5 = fmaxf(0.f, bfhi(hv.z)*sc1.y + sh1.y);
    float v6 = fmaxf(0.f, bflo(hv.w)*sc1.z + sh1.z);
    float v7 = fmaxf(0.f, bfhi(hv.w)*sc1.w + sh1.w);
    uint4 o = {pack2(v0,v1), pack2(v2,v3), pack2(v4,v5), pack2(v6,v7)};
    *(uint4*)(x1bf + base) = o;
}

// ---- layer 2 ---------------------------------------------------------------

// agg2bf[n][f] = bf16(mean over in-edges of x1bf[src][f]); 16 threads x 16B/node
__global__ void __launch_bounds__(256) k_agg2(
        const ushort* __restrict__ x1bf, const int* __restrict__ offs,
        const int* __restrict__ ssrc, ushort* __restrict__ agg2bf) {
    int t = threadIdx.x;
    int n = blockIdx.x * 16 + (t >> 4);
    int c8 = (t & 15) * 8;
    int s0 = offs[n], s1 = offs[n + 1];
    float acc[8] = {0,0,0,0,0,0,0,0};
    int j = s0;
    for (; j + 3 < s1; j += 4) {               // 4 gathers in flight
        int sa = ssrc[j], sb = ssrc[j+1], sc = ssrc[j+2], sd = ssrc[j+3];
        uint4 va = *(const uint4*)(x1bf + (size_t)sa * F + c8);
        uint4 vb = *(const uint4*)(x1bf + (size_t)sb * F + c8);
        uint4 vc = *(const uint4*)(x1bf + (size_t)sc * F + c8);
        uint4 vd = *(const uint4*)(x1bf + (size_t)sd * F + c8);
        acc[0] += (bflo(va.x)+bflo(vb.x)) + (bflo(vc.x)+bflo(vd.x));
        acc[1] += (bfhi(va.x)+bfhi(vb.x)) + (bfhi(vc.x)+bfhi(vd.x));
        acc[2] += (bflo(va.y)+bflo(vb.y)) + (bflo(vc.y)+bflo(vd.y));
        acc[3] += (bfhi(va.y)+bfhi(vb.y)) + (bfhi(vc.y)+bfhi(vd.y));
        acc[4] += (bflo(va.z)+bflo(vb.z)) + (bflo(vc.z)+bflo(vd.z));
        acc[5] += (bfhi(va.z)+bfhi(vb.z)) + (bfhi(vc.z)+bfhi(vd.z));
        acc[6] += (bflo(va.w)+bflo(vb.w)) + (bflo(vc.w)+bflo(vd.w));
        acc[7] += (bfhi(va.w)+bfhi(vb.w)) + (bfhi(vc.w)+bfhi(vd.w));
    }
    for (; j < s1; ++j) {
        uint4 v = *(const uint4*)(x1bf + (size_t)ssrc[j] * F + c8);
        acc[0] += bflo(v.x); acc[1] += bfhi(v.x);
        acc[2] += bflo(v.y); acc[3] += bfhi(v.y);
        acc[4] += bflo(v.z); acc[5] += bfhi(v.z);
        acc[6] += bflo(v.w); acc[7] += bfhi(v.w);
    }
    int dg = s1 - s0;
    float inv = 1.0f / (float)(dg > 1 ? dg : 1);
    uint4 o = {pack2(acc[0]*inv, acc[1]*inv), pack2(acc[2]*inv, acc[3]*inv),
               pack2(acc[4]*inv, acc[5]*inv), pack2(acc[6]*inv, acc[7]*inv)};
    *(uint4*)(agg2bf + (size_t)n * F + c8) = o;
}

// h2 = agg2 @ W2l^T + b2 + x1 @ W2r^T via bf16 MFMA; BN stats fused.
__global__ void __launch_bounds__(256) k_lin2(
        const ushort* __restrict__ agg2bf, const ushort* __restrict__ x1bf,
        const ushort* __restrict__ Wcat, const float* __restrict__ b2,
        ushort* __restrict__ h2bf, float* __restrict__ stats) {
    __shared__ ushort sOut[128 * 136];         // 128x128 bf16 tile, stride 136
    __shared__ float sred[256];
    int tid = threadIdx.x;
    int wave = tid >> 6, lane = tid & 63;
    int quad = lane >> 4, l16 = lane & 15;
    int n0 = blockIdx.x * 128 + wave * 32;

    s16x8 a[2][8];
    #pragma unroll
    for (int mt = 0; mt < 2; ++mt) {
        int node = n0 + mt * 16 + l16;
        if (node >= N_NODES) node = N_NODES - 1;   // clamp; stores masked below
        #pragma unroll
        for (int ks = 0; ks < 8; ++ks) {
            const ushort* src = (ks < 4) ? agg2bf : x1bf;
            B8 tm;
            tm.u = *(const uint4*)(src + (size_t)node * F + (ks & 3) * 32 + quad * 8);
            a[mt][ks] = tm.s;
        }
    }

    #pragma unroll
    for (int nt = 0; nt < 8; ++nt) {
        int fb = nt * 16 + l16;
        s16x8 b[8];
        #pragma unroll
        for (int ks = 0; ks < 8; ++ks) {
            B8 tm;
            tm.u = *(const uint4*)(Wcat + fb * 256 + ks * 32 + quad * 8);
            b[ks] = tm.s;
        }
        f32x4 acc0 = {0.f, 0.f, 0.f, 0.f};
        f32x4 acc1 = {0.f, 0.f, 0.f, 0.f};
        #pragma unroll
        for (int ks = 0; ks < 8; ++ks) {
            acc0 = __builtin_amdgcn_mfma_f32_16x16x32_bf16(a[0][ks], b[ks], acc0, 0, 0, 0);
            acc1 = __builtin_amdgcn_mfma_f32_16x16x32_bf16(a[1][ks], b[ks], acc1, 0, 0, 0);
        }
        float bb = b2[fb];
        #pragma unroll
        for (int r = 0; r < 4; ++r) {
            int row0 = wave * 32 + quad * 4 + r;          // mt = 0
            sOut[row0 * 136 + fb]        = f2bf(acc0[r] + bb);
            sOut[(row0 + 16) * 136 + fb] = f2bf(acc1[r] + bb);
        }
    }
    __syncthreads();

    #pragma unroll
    for (int p = 0; p < 8; ++p) {
        int row = p * 16 + (tid >> 4);
        int node = blockIdx.x * 128 + row;
        if (node < N_NODES) {
            int c0 = (tid & 15) * 8;
            uint4 v = *(const uint4*)&sOut[row * 136 + c0];
            *(uint4*)(h2bf + (size_t)node * F + c0) = v;
        }
    }

    int f = tid & 127, half = tid >> 7;
    float s = 0.f, s2 = 0.f;
    for (int r = half * 64; r < half * 64 + 64; ++r) {
        int node = blockIdx.x * 128 + r;
        if (node >= N_NODES) break;
        float v = bf2f(sOut[r * 136 + f]);
        s += v; s2 += v * v;
    }
    if (half) { sred[f] = s; sred[128 + f] = s2; }
    __syncthreads();
    if (!half) {
        s += sred[f]; s2 += sred[128 + f];
        atomicAdd(&stats[f], s);
        atomicAdd(&stats[F + f], s2);
    }
}

// ---- pooling ---------------------------------------------------------------

__global__ void k_pool(const ushort* __restrict__ x1bf, const ushort* __restrict__ h2bf,
                       const float* __restrict__ scsh2, const int* __restrict__ batch,
                       float* __restrict__ outacc) {
    int f = threadIdx.x;
    int n0 = blockIdx.x * 128;
    int n1 = min(n0 + 128, N_NODES);
    float sc = scsh2[f], sh = scsh2[F + f];
    float acc = 0.f;
    int curg = batch[n0];
    for (int n = n0; n < n1; ++n) {
        int g = batch[n];
        if (g != curg) {
            atomicAdd(&outacc[curg * F + f], acc);
            acc = 0.f; curg = g;
        }
        float v1 = bf2f(x1bf[(size_t)n * F + f]);
        float v2 = fmaxf(0.f, bf2f(h2bf[(size_t)n * F + f]) * sc + sh);
        acc += v1 + v2;
    }
    atomicAdd(&outacc[curg * F + f], acc);
}

__global__ void k_out(const float* __restrict__ outacc, const int* __restrict__ gstart,
                      float* __restrict__ out) {
    int i = blockIdx.x * 256 + threadIdx.x;
    if (i >= NUM_GRAPHS * F) return;
    int g = i >> 7;
    int c = gstart[g + 1] - gstart[g];
    out[i] = outacc[i] / (float)(c > 1 ? c : 1);
}

}  // namespace

extern "C" void kernel_launch(void* const* d_in, const int* in_sizes, int n_in,
                              void* d_out, int out_size, void* d_ws, size_t ws_size,
                              hipStream_t stream) {
    const float* x     = (const float*)d_in[0];
    const int*   ei    = (const int*)d_in[1];    // [2, E]: row0 = src, row1 = dst
    const int*   batch = (const int*)d_in[2];
    const float* W1l   = (const float*)d_in[3];
    const float* b1    = (const float*)d_in[4];
    const float* W1r   = (const float*)d_in[5];
    const float* g1    = (const float*)d_in[6];
    const float* be1   = (const float*)d_in[7];
    const float* W2l   = (const float*)d_in[8];
    const float* b2    = (const float*)d_in[9];
    const float* W2r   = (const float*)d_in[10];
    const float* g2    = (const float*)d_in[11];
    const float* be2   = (const float*)d_in[12];
    float* out = (float*)d_out;

    char* w = (char*)d_ws;
    size_t o = 0;
    auto alloc = [&](size_t bytes) {
        void* p = w + o;
        o += (bytes + 511) & ~(size_t)511;
        return p;
    };
    int*    deg    = (int*)alloc((size_t)N_NODES * 4);
    int*    offs   = (int*)alloc((size_t)(N_NODES + 1) * 4);
    int*    gcount = (int*)alloc((size_t)NBUCK * CB * 4);
    int*    ssrc   = (int*)alloc((size_t)N_EDGES * 4);
    uint*   epk    = (uint*)alloc((size_t)N_EDGES * 4);
    int*    bsums  = (int*)alloc(2048);
    int*    gstart = (int*)alloc((NUM_GRAPHS + 1) * 4);
    float*  stats  = (float*)alloc(512 * 4);   // [s1,s1sq | s2,s2sq]
    float*  scsh   = (float*)alloc(512 * 4);   // [sc1,sh1 | sc2,sh2]
    ushort* Wcat   = (ushort*)alloc((size_t)F * 256 * 2);
    float*  outacc = (float*)alloc((size_t)NUM_GRAPHS * F * 4);
    float*  agg1   = (float*)alloc((size_t)N_NODES * 8 * 4);
    ushort* h1bf   = (ushort*)alloc((size_t)N_NODES * F * 2);
    ushort* x1bf   = (ushort*)alloc((size_t)N_NODES * F * 2);
    ushort* agg2bf = (ushort*)alloc((size_t)N_NODES * F * 2);
    ushort* h2bf   = (ushort*)alloc((size_t)N_NODES * F * 2);

    hipMemsetAsync(deg,    0, (size_t)N_NODES * 4, stream);
    hipMemsetAsync(stats,  0, 512 * 4, stream);
    hipMemsetAsync(outacc, 0, (size_t)NUM_GRAPHS * F * 4, stream);

    // CSR-by-dst: chunk histograms -> scans -> partition -> per-bucket rank
    k_histA<<<CB, 256, 0, stream>>>(ei, deg, gcount);
    k_scan1<<<SCAN_NB, 256, 0, stream>>>(deg, offs, bsums);
    k_scan2<<<1, 512, 0, stream>>>(bsums);
    k_scan3<<<SCAN_NB, 256, 0, stream>>>(offs, bsums);
    k_scanG<<<1, 1024, 0, stream>>>(gcount, NBUCK * CB);
    k_part <<<CB, 256, 0, stream>>>(ei, gcount, epk);
    k_rank <<<NBUCK, 512, 0, stream>>>(epk, gcount, offs, ssrc);
    k_bound<<<(N_NODES + 255) / 256, 256, 0, stream>>>(batch, gstart);
    k_packbf<<<64, 256, 0, stream>>>(W2l, W2r, Wcat);

    // layer 1
    k_agg1  <<<(N_NODES + 255) / 256, 256, 0, stream>>>(x, offs, ssrc, agg1);
    k_lin1  <<<N_NODES / 32, 128, 0, stream>>>(x, agg1, W1l, b1, W1r, h1bf, stats);
    k_bnfin <<<1, 128, 0, stream>>>(stats, g1, be1, scsh);
    k_bnrelu<<<(N_NODES * F / 8) / 256, 256, 0, stream>>>(h1bf, scsh, x1bf);

    // layer 2 (bf16 + MFMA; stats fused into k_lin2)
    k_agg2  <<<N_NODES / 16, 256, 0, stream>>>(x1bf, offs, ssrc, agg2bf);
    k_lin2  <<<(N_NODES + 127) / 128, 256, 0, stream>>>(agg2bf, x1bf, Wcat, b2,
                                                        h2bf, stats + 256);
    k_bnfin <<<1, 128, 0, stream>>>(stats + 256, g2, be2, scsh + 256);

    // residual + pool
    k_pool<<<(N_NODES + 127) / 128, 128, 0, stream>>>(x1bf, h2bf, scsh + 256, batch, outacc);
    k_out <<<(NUM_GRAPHS * F + 255) / 256, 256, 0, stream>>>(outacc, gstart, out);
}

// Round 5
// 490.777 us; speedup vs baseline: 1.7746x; 1.0624x over previous
//
#include <hip/hip_runtime.h>
#include <cstdint>
#include <cstddef>

namespace {

constexpr int N_NODES = 100000;
constexpr int N_EDGES = 1600000;
constexpr int NUM_GRAPHS = 128;
constexpr int F = 128;
constexpr float BN_EPS = 1e-5f;
constexpr int SCAN_NB = (N_NODES + 255) / 256;   // 391

// bucket sort params: 196 buckets x 512 nodes; 200 chunks x 8000 edges
constexpr int W_BUCK = 512;
constexpr int NBUCK = (N_NODES + W_BUCK - 1) / W_BUCK;  // 196
constexpr int CB = 200;
constexpr int CHUNK = N_EDGES / CB;                      // 8000

typedef float f32x4 __attribute__((ext_vector_type(4)));
typedef short s16x8 __attribute__((ext_vector_type(8)));
union B8 { uint4 u; s16x8 s; };

__device__ inline ushort f2bf(float x) {         // RNE fp32 -> bf16
    uint u = __float_as_uint(x);
    u += 0x7fffu + ((u >> 16) & 1u);
    return (ushort)(u >> 16);
}
__device__ inline float bf2f(ushort s) { return __uint_as_float(((uint)s) << 16); }
__device__ inline uint pack2(float lo, float hi) {
    return (uint)f2bf(lo) | ((uint)f2bf(hi) << 16);
}
__device__ inline float bflo(uint u) { return __uint_as_float(u << 16); }
__device__ inline float bfhi(uint u) { return __uint_as_float(u & 0xffff0000u); }

// ---- CSR-by-dst via 2-level bucket sort (line-local writes) -----------------

__global__ void __launch_bounds__(256) k_histA(const int* __restrict__ ei,
                                               int* __restrict__ deg,
                                               int* __restrict__ gcount) {
    __shared__ int bins[NBUCK];
    int t = threadIdx.x;
    for (int i = t; i < NBUCK; i += 256) bins[i] = 0;
    __syncthreads();
    int e0 = blockIdx.x * CHUNK;
    for (int i = t; i < CHUNK; i += 256) {
        int d = ei[N_EDGES + e0 + i];
        atomicAdd(&deg[d], 1);
        atomicAdd(&bins[d >> 9], 1);
    }
    __syncthreads();
    for (int i = t; i < NBUCK; i += 256) gcount[i * CB + blockIdx.x] = bins[i];
}

__global__ void __launch_bounds__(1024) k_scanG(int* __restrict__ g, int n) {
    __shared__ int ts[1024];
    int t = threadIdx.x;
    int per = (n + 1023) / 1024;
    int lo = t * per, hi = min(lo + per, n);
    int s = 0;
    for (int i = lo; i < hi; ++i) s += g[i];
    ts[t] = s;
    __syncthreads();
    #pragma unroll
    for (int d = 1; d < 1024; d <<= 1) {
        int v = (t >= d) ? ts[t - d] : 0;
        __syncthreads();
        ts[t] += v;
        __syncthreads();
    }
    int run = ts[t] - s;
    for (int i = lo; i < hi; ++i) {
        int v = g[i];
        g[i] = run;
        run += v;
    }
}

__global__ void __launch_bounds__(256) k_part(const int* __restrict__ ei,
                                              const int* __restrict__ goffs,
                                              uint* __restrict__ epk) {
    __shared__ int cur[NBUCK];
    int t = threadIdx.x;
    for (int i = t; i < NBUCK; i += 256) cur[i] = goffs[i * CB + blockIdx.x];
    __syncthreads();
    int e0 = blockIdx.x * CHUNK;
    for (int i = t; i < CHUNK; i += 256) {
        int d = ei[N_EDGES + e0 + i];
        int s = ei[e0 + i];
        int p = atomicAdd(&cur[d >> 9], 1);
        epk[p] = ((uint)s << 9) | (uint)(d & 511);
    }
}

__global__ void __launch_bounds__(512) k_rank(const uint* __restrict__ epk,
                                              const int* __restrict__ goffs,
                                              const int* __restrict__ offs,
                                              int* __restrict__ ssrc) {
    __shared__ int cur[W_BUCK];
    int b = blockIdx.x, t = threadIdx.x;
    int node = b * W_BUCK + t;
    cur[t] = (node < N_NODES) ? offs[node] : 0;
    __syncthreads();
    int s0 = goffs[b * CB];
    int s1 = (b + 1 < NBUCK) ? goffs[(b + 1) * CB] : N_EDGES;
    for (int i = s0 + t; i < s1; i += 512) {
        uint u = epk[i];
        int p = atomicAdd(&cur[u & 511u], 1);
        ssrc[p] = (int)(u >> 9);
    }
}

// ---- node-offset scans ------------------------------------------------------

__global__ void k_scan1(const int* __restrict__ deg, int* __restrict__ offs,
                        int* __restrict__ bsums) {
    __shared__ int tmp[256];
    int i = blockIdx.x * 256 + threadIdx.x;
    int v = (i < N_NODES) ? deg[i] : 0;
    tmp[threadIdx.x] = v;
    __syncthreads();
    #pragma unroll
    for (int d = 1; d < 256; d <<= 1) {
        int t = (threadIdx.x >= d) ? tmp[threadIdx.x - d] : 0;
        __syncthreads();
        tmp[threadIdx.x] += t;
        __syncthreads();
    }
    if (i < N_NODES) offs[i] = tmp[threadIdx.x] - v;
    if (threadIdx.x == 255) bsums[blockIdx.x] = tmp[255];
}

__global__ void k_scan2(int* __restrict__ bsums) {
    __shared__ int tmp[512];
    int i = threadIdx.x;
    int v = (i < SCAN_NB) ? bsums[i] : 0;
    tmp[i] = v;
    __syncthreads();
    #pragma unroll
    for (int d = 1; d < 512; d <<= 1) {
        int t = (i >= d) ? tmp[i - d] : 0;
        __syncthreads();
        tmp[i] += t;
        __syncthreads();
    }
    if (i < SCAN_NB) bsums[i] = tmp[i] - v;
}

__global__ void k_scan3(int* __restrict__ offs, const int* __restrict__ bsums) {
    int i = blockIdx.x * 256 + threadIdx.x;
    if (i < N_NODES) offs[i] += bsums[blockIdx.x];
    if (i == 0) offs[N_NODES] = N_EDGES;
}

// ---- graph segment boundaries (batch is sorted) ----------------------------

__global__ void k_bound(const int* __restrict__ batch, int* __restrict__ gstart) {
    int i = blockIdx.x * 256 + threadIdx.x;
    if (i >= N_NODES) return;
    int b = batch[i];
    if (i == 0) {
        for (int g = 0; g <= b; ++g) gstart[g] = 0;
    } else {
        int p = batch[i - 1];
        if (p != b) for (int g = p + 1; g <= b; ++g) gstart[g] = i;
    }
    if (i == N_NODES - 1) {
        for (int g = b + 1; g <= NUM_GRAPHS; ++g) gstart[g] = N_NODES;
    }
}

// ---- weight packs -----------------------------------------------------------

// layer 2: Wcat[f][0:128]=W2l[f][:], Wcat[f][128:256]=W2r[f][:], bf16
__global__ void k_packbf(const float* __restrict__ Wl, const float* __restrict__ Wr,
                         ushort* __restrict__ Wcat) {
    int i = blockIdx.x * 256 + threadIdx.x;    // 16384 exact
    int f = i >> 7, k = i & 127;
    Wcat[f * 256 + k]       = f2bf(Wl[i]);
    Wcat[f * 256 + 128 + k] = f2bf(Wr[i]);
}

// layer 1: Wcat1[f][32] bf16: k<8 -> W1r[f][k] (pairs x), 8..15 -> W1l[f][k-8]
// (pairs agg1), 16..31 -> 0 (K-pad for the 16x16x32 MFMA)
__global__ void k_packbf1(const float* __restrict__ W1l, const float* __restrict__ W1r,
                          ushort* __restrict__ Wcat1) {
    int i = blockIdx.x * 256 + threadIdx.x;    // 4096 exact
    int f = i >> 5, k = i & 31;
    float v = (k < 8) ? W1r[f * 8 + k] : ((k < 16) ? W1l[f * 8 + (k - 8)] : 0.f);
    Wcat1[i] = f2bf(v);
}

// ---- layer 1 ---------------------------------------------------------------

// xa[n][32] bf16 = [x[n] (8) | mean_j x[src] (8) | zeros (16)]  — one 64B line
__global__ void k_agg1(const float* __restrict__ x, const int* __restrict__ offs,
                       const int* __restrict__ ssrc, ushort* __restrict__ xa) {
    int n = blockIdx.x * 256 + threadIdx.x;
    if (n >= N_NODES) return;
    int s0 = offs[n], s1 = offs[n + 1];
    float a0=0,a1=0,a2=0,a3=0,a4=0,a5=0,a6=0,a7=0;
    for (int j = s0; j < s1; ++j) {
        const float4* xp = (const float4*)(x + (size_t)ssrc[j] * 8);
        float4 b0 = xp[0], b1 = xp[1];
        a0+=b0.x; a1+=b0.y; a2+=b0.z; a3+=b0.w;
        a4+=b1.x; a5+=b1.y; a6+=b1.z; a7+=b1.w;
    }
    int dg = s1 - s0;
    float inv = 1.0f / (float)(dg > 1 ? dg : 1);
    const float4* xp = (const float4*)(x + (size_t)n * 8);
    float4 x0 = xp[0], x1v = xp[1];
    ushort* row = xa + (size_t)n * 32;
    uint4 o0 = {pack2(x0.x, x0.y), pack2(x0.z, x0.w), pack2(x1v.x, x1v.y), pack2(x1v.z, x1v.w)};
    uint4 o1 = {pack2(a0*inv, a1*inv), pack2(a2*inv, a3*inv),
                pack2(a4*inv, a5*inv), pack2(a6*inv, a7*inv)};
    uint4 z = {0u, 0u, 0u, 0u};
    *(uint4*)(row)      = o0;
    *(uint4*)(row + 8)  = o1;
    *(uint4*)(row + 16) = z;
    *(uint4*)(row + 24) = z;
}

// h1bf = bf16(xa @ Wcat1^T + b1) via one MFMA per f-tile; fp32 BN stats fused.
// Block 256 = 4 waves; wave = 16 nodes; 64 nodes/block.
__global__ void __launch_bounds__(256) k_lin1(
        const ushort* __restrict__ xa, const ushort* __restrict__ Wcat1,
        const float* __restrict__ b1, ushort* __restrict__ h1bf,
        float* __restrict__ stats) {
    __shared__ ushort sOut[64 * 140];          // stride 140: 4-quad conflict-free
    __shared__ float sred[256];
    int tid = threadIdx.x;
    int wave = tid >> 6, lane = tid & 63;
    int quad = lane >> 4, l16 = lane & 15;
    int n0 = blockIdx.x * 64;

    int node = n0 + wave * 16 + l16;
    int cn = (node < N_NODES) ? node : N_NODES - 1;  // clamp; stores masked below
    B8 ta;
    ta.u = *(const uint4*)(xa + (size_t)cn * 32 + quad * 8);

    #pragma unroll
    for (int nt = 0; nt < 8; ++nt) {
        int fb = nt * 16 + l16;
        B8 tb;
        tb.u = *(const uint4*)(Wcat1 + fb * 32 + quad * 8);
        f32x4 acc = {0.f, 0.f, 0.f, 0.f};
        acc = __builtin_amdgcn_mfma_f32_16x16x32_bf16(ta.s, tb.s, acc, 0, 0, 0);
        float bb = b1[fb];
        #pragma unroll
        for (int r = 0; r < 4; ++r) {
            int row = wave * 16 + quad * 4 + r;
            sOut[row * 140 + fb] = f2bf(acc[r] + bb);
        }
    }
    __syncthreads();

    // coalesced write of the 64x128 bf16 tile
    #pragma unroll
    for (int p = 0; p < 4; ++p) {
        int row = p * 16 + (tid >> 4);
        int nd = n0 + row;
        if (nd < N_NODES) {
            int c0 = (tid & 15) * 8;
            uint4 v = *(const uint4*)&sOut[row * 140 + c0];
            *(uint4*)(h1bf + (size_t)nd * F + c0) = v;
        }
    }

    // fused BN stats from the staged tile
    int f = tid & 127, half = tid >> 7;
    float s = 0.f, s2 = 0.f;
    for (int r = half * 32; r < half * 32 + 32; ++r) {
        if (n0 + r >= N_NODES) break;
        float v = bf2f(sOut[r * 140 + f]);
        s += v; s2 += v * v;
    }
    if (half) { sred[f] = s; sred[128 + f] = s2; }
    __syncthreads();
    if (!half) {
        s += sred[f]; s2 += sred[128 + f];
        atomicAdd(&stats[f], s);
        atomicAdd(&stats[F + f], s2);
    }
}

__global__ void k_bnfin(const float* __restrict__ stats, const float* __restrict__ gamma,
                        const float* __restrict__ beta, float* __restrict__ scsh) {
    int f = threadIdx.x;
    float mu  = stats[f] * (1.0f / N_NODES);
    float var = stats[F + f] * (1.0f / N_NODES) - mu * mu;
    float sc  = gamma[f] * rsqrtf(var + BN_EPS);
    scsh[f] = sc;
    scsh[F + f] = beta[f] - mu * sc;
}

// x1bf = bf16(relu(scale*h1 + shift))
__global__ void k_bnrelu(const ushort* __restrict__ h, const float* __restrict__ scsh,
                         ushort* __restrict__ x1bf) {
    int i = blockIdx.x * 256 + threadIdx.x;      // N*128/8 = 1.6M exact
    int base = i * 8;
    int f = base & (F - 1);
    float4 sc0 = *(const float4*)(scsh + f);
    float4 sc1 = *(const float4*)(scsh + f + 4);
    float4 sh0 = *(const float4*)(scsh + F + f);
    float4 sh1 = *(const float4*)(scsh + F + f + 4);
    uint4 hv = *(const uint4*)(h + base);
    float v0 = fmaxf(0.f, bflo(hv.x)*sc0.x + sh0.x);
    float v1 = fmaxf(0.f, bfhi(hv.x)*sc0.y + sh0.y);
    float v2 = fmaxf(0.f, bflo(hv.y)*sc0.z + sh0.z);
    float v3 = fmaxf(0.f, bfhi(hv.y)*sc0.w + sh0.w);
    float v4 = fmaxf(0.f, bflo(hv.z)*sc1.x + sh1.x);
    float v5 = fmaxf(0.f, bfhi(hv.z)*sc1.y + sh1.y);
    float v6 = fmaxf(0.f, bflo(hv.w)*sc1.z + sh1.z);
    float v7 = fmaxf(0.f, bfhi(hv.w)*sc1.w + sh1.w);
    uint4 o = {pack2(v0,v1), pack2(v2,v3), pack2(v4,v5), pack2(v6,v7)};
    *(uint4*)(x1bf + base) = o;
}

// ---- layer 2 ---------------------------------------------------------------

// agg2bf[n][f] = bf16(mean over in-edges of x1bf[src][f]); 16 threads x 16B/node
__global__ void __launch_bounds__(256) k_agg2(
        const ushort* __restrict__ x1bf, const int* __restrict__ offs,
        const int* __restrict__ ssrc, ushort* __restrict__ agg2bf) {
    int t = threadIdx.x;
    int n = blockIdx.x * 16 + (t >> 4);
    int c8 = (t & 15) * 8;
    int s0 = offs[n], s1 = offs[n + 1];
    float acc[8] = {0,0,0,0,0,0,0,0};
    int j = s0;
    for (; j + 3 < s1; j += 4) {               // 4 gathers in flight
        int sa = ssrc[j], sb = ssrc[j+1], sc = ssrc[j+2], sd = ssrc[j+3];
        uint4 va = *(const uint4*)(x1bf + (size_t)sa * F + c8);
        uint4 vb = *(const uint4*)(x1bf + (size_t)sb * F + c8);
        uint4 vc = *(const uint4*)(x1bf + (size_t)sc * F + c8);
        uint4 vd = *(const uint4*)(x1bf + (size_t)sd * F + c8);
        acc[0] += (bflo(va.x)+bflo(vb.x)) + (bflo(vc.x)+bflo(vd.x));
        acc[1] += (bfhi(va.x)+bfhi(vb.x)) + (bfhi(vc.x)+bfhi(vd.x));
        acc[2] += (bflo(va.y)+bflo(vb.y)) + (bflo(vc.y)+bflo(vd.y));
        acc[3] += (bfhi(va.y)+bfhi(vb.y)) + (bfhi(vc.y)+bfhi(vd.y));
        acc[4] += (bflo(va.z)+bflo(vb.z)) + (bflo(vc.z)+bflo(vd.z));
        acc[5] += (bfhi(va.z)+bfhi(vb.z)) + (bfhi(vc.z)+bfhi(vd.z));
        acc[6] += (bflo(va.w)+bflo(vb.w)) + (bflo(vc.w)+bflo(vd.w));
        acc[7] += (bfhi(va.w)+bfhi(vb.w)) + (bfhi(vc.w)+bfhi(vd.w));
    }
    for (; j < s1; ++j) {
        uint4 v = *(const uint4*)(x1bf + (size_t)ssrc[j] * F + c8);
        acc[0] += bflo(v.x); acc[1] += bfhi(v.x);
        acc[2] += bflo(v.y); acc[3] += bfhi(v.y);
        acc[4] += bflo(v.z); acc[5] += bfhi(v.z);
        acc[6] += bflo(v.w); acc[7] += bfhi(v.w);
    }
    int dg = s1 - s0;
    float inv = 1.0f / (float)(dg > 1 ? dg : 1);
    uint4 o = {pack2(acc[0]*inv, acc[1]*inv), pack2(acc[2]*inv, acc[3]*inv),
               pack2(acc[4]*inv, acc[5]*inv), pack2(acc[6]*inv, acc[7]*inv)};
    *(uint4*)(agg2bf + (size_t)n * F + c8) = o;
}

// h2 = agg2 @ W2l^T + b2 + x1 @ W2r^T via bf16 MFMA; BN stats fused.
__global__ void __launch_bounds__(256) k_lin2(
        const ushort* __restrict__ agg2bf, const ushort* __restrict__ x1bf,
        const ushort* __restrict__ Wcat, const float* __restrict__ b2,
        ushort* __restrict__ h2bf, float* __restrict__ stats) {
    __shared__ ushort sOut[128 * 136];         // 128x128 bf16 tile, stride 136
    __shared__ float sred[256];
    int tid = threadIdx.x;
    int wave = tid >> 6, lane = tid & 63;
    int quad = lane >> 4, l16 = lane & 15;
    int n0 = blockIdx.x * 128 + wave * 32;

    s16x8 a[2][8];
    #pragma unroll
    for (int mt = 0; mt < 2; ++mt) {
        int node = n0 + mt * 16 + l16;
        if (node >= N_NODES) node = N_NODES - 1;   // clamp; stores masked below
        #pragma unroll
        for (int ks = 0; ks < 8; ++ks) {
            const ushort* src = (ks < 4) ? agg2bf : x1bf;
            B8 tm;
            tm.u = *(const uint4*)(src + (size_t)node * F + (ks & 3) * 32 + quad * 8);
            a[mt][ks] = tm.s;
        }
    }

    #pragma unroll
    for (int nt = 0; nt < 8; ++nt) {
        int fb = nt * 16 + l16;
        s16x8 b[8];
        #pragma unroll
        for (int ks = 0; ks < 8; ++ks) {
            B8 tm;
            tm.u = *(const uint4*)(Wcat + fb * 256 + ks * 32 + quad * 8);
            b[ks] = tm.s;
        }
        f32x4 acc0 = {0.f, 0.f, 0.f, 0.f};
        f32x4 acc1 = {0.f, 0.f, 0.f, 0.f};
        #pragma unroll
        for (int ks = 0; ks < 8; ++ks) {
            acc0 = __builtin_amdgcn_mfma_f32_16x16x32_bf16(a[0][ks], b[ks], acc0, 0, 0, 0);
            acc1 = __builtin_amdgcn_mfma_f32_16x16x32_bf16(a[1][ks], b[ks], acc1, 0, 0, 0);
        }
        float bb = b2[fb];
        #pragma unroll
        for (int r = 0; r < 4; ++r) {
            int row0 = wave * 32 + quad * 4 + r;          // mt = 0
            sOut[row0 * 136 + fb]        = f2bf(acc0[r] + bb);
            sOut[(row0 + 16) * 136 + fb] = f2bf(acc1[r] + bb);
        }
    }
    __syncthreads();

    #pragma unroll
    for (int p = 0; p < 8; ++p) {
        int row = p * 16 + (tid >> 4);
        int node = blockIdx.x * 128 + row;
        if (node < N_NODES) {
            int c0 = (tid & 15) * 8;
            uint4 v = *(const uint4*)&sOut[row * 136 + c0];
            *(uint4*)(h2bf + (size_t)node * F + c0) = v;
        }
    }

    int f = tid & 127, half = tid >> 7;
    float s = 0.f, s2 = 0.f;
    for (int r = half * 64; r < half * 64 + 64; ++r) {
        int node = blockIdx.x * 128 + r;
        if (node >= N_NODES) break;
        float v = bf2f(sOut[r * 136 + f]);
        s += v; s2 += v * v;
    }
    if (half) { sred[f] = s; sred[128 + f] = s2; }
    __syncthreads();
    if (!half) {
        s += sred[f]; s2 += sred[128 + f];
        atomicAdd(&stats[f], s);
        atomicAdd(&stats[F + f], s2);
    }
}

// ---- pooling ---------------------------------------------------------------

__global__ void k_pool(const ushort* __restrict__ x1bf, const ushort* __restrict__ h2bf,
                       const float* __restrict__ scsh2, const int* __restrict__ batch,
                       float* __restrict__ outacc) {
    int f = threadIdx.x;
    int n0 = blockIdx.x * 128;
    int n1 = min(n0 + 128, N_NODES);
    float sc = scsh2[f], sh = scsh2[F + f];
    float acc = 0.f;
    int curg = batch[n0];
    for (int n = n0; n < n1; ++n) {
        int g = batch[n];
        if (g != curg) {
            atomicAdd(&outacc[curg * F + f], acc);
            acc = 0.f; curg = g;
        }
        float v1 = bf2f(x1bf[(size_t)n * F + f]);
        float v2 = fmaxf(0.f, bf2f(h2bf[(size_t)n * F + f]) * sc + sh);
        acc += v1 + v2;
    }
    atomicAdd(&outacc[curg * F + f], acc);
}

__global__ void k_out(const float* __restrict__ outacc, const int* __restrict__ gstart,
                      float* __restrict__ out) {
    int i = blockIdx.x * 256 + threadIdx.x;
    if (i >= NUM_GRAPHS * F) return;
    int g = i >> 7;
    int c = gstart[g + 1] - gstart[g];
    out[i] = outacc[i] / (float)(c > 1 ? c : 1);
}

}  // namespace

extern "C" void kernel_launch(void* const* d_in, const int* in_sizes, int n_in,
                              void* d_out, int out_size, void* d_ws, size_t ws_size,
                              hipStream_t stream) {
    const float* x     = (const float*)d_in[0];
    const int*   ei    = (const int*)d_in[1];    // [2, E]: row0 = src, row1 = dst
    const int*   batch = (const int*)d_in[2];
    const float* W1l   = (const float*)d_in[3];
    const float* b1    = (const float*)d_in[4];
    const float* W1r   = (const float*)d_in[5];
    const float* g1    = (const float*)d_in[6];
    const float* be1   = (const float*)d_in[7];
    const float* W2l   = (const float*)d_in[8];
    const float* b2    = (const float*)d_in[9];
    const float* W2r   = (const float*)d_in[10];
    const float* g2    = (const float*)d_in[11];
    const float* be2   = (const float*)d_in[12];
    float* out = (float*)d_out;

    char* w = (char*)d_ws;
    size_t o = 0;
    auto alloc = [&](size_t bytes) {
        void* p = w + o;
        o += (bytes + 511) & ~(size_t)511;
        return p;
    };
    int*    deg    = (int*)alloc((size_t)N_NODES * 4);
    int*    offs   = (int*)alloc((size_t)(N_NODES + 1) * 4);
    int*    gcount = (int*)alloc((size_t)NBUCK * CB * 4);
    int*    ssrc   = (int*)alloc((size_t)N_EDGES * 4);
    uint*   epk    = (uint*)alloc((size_t)N_EDGES * 4);
    int*    bsums  = (int*)alloc(2048);
    int*    gstart = (int*)alloc((NUM_GRAPHS + 1) * 4);
    float*  stats  = (float*)alloc(512 * 4);   // [s1,s1sq | s2,s2sq]
    float*  scsh   = (float*)alloc(512 * 4);   // [sc1,sh1 | sc2,sh2]
    ushort* Wcat   = (ushort*)alloc((size_t)F * 256 * 2);
    ushort* Wcat1  = (ushort*)alloc((size_t)F * 32 * 2);
    float*  outacc = (float*)alloc((size_t)NUM_GRAPHS * F * 4);
    ushort* xa     = (ushort*)alloc((size_t)N_NODES * 32 * 2);
    ushort* h1bf   = (ushort*)alloc((size_t)N_NODES * F * 2);
    ushort* x1bf   = (ushort*)alloc((size_t)N_NODES * F * 2);
    ushort* agg2bf = (ushort*)alloc((size_t)N_NODES * F * 2);
    ushort* h2bf   = (ushort*)alloc((size_t)N_NODES * F * 2);

    hipMemsetAsync(deg,    0, (size_t)N_NODES * 4, stream);
    hipMemsetAsync(stats,  0, 512 * 4, stream);
    hipMemsetAsync(outacc, 0, (size_t)NUM_GRAPHS * F * 4, stream);

    // CSR-by-dst: chunk histograms -> scans -> partition -> per-bucket rank
    k_histA<<<CB, 256, 0, stream>>>(ei, deg, gcount);
    k_scan1<<<SCAN_NB, 256, 0, stream>>>(deg, offs, bsums);
    k_scan2<<<1, 512, 0, stream>>>(bsums);
    k_scan3<<<SCAN_NB, 256, 0, stream>>>(offs, bsums);
    k_scanG<<<1, 1024, 0, stream>>>(gcount, NBUCK * CB);
    k_part <<<CB, 256, 0, stream>>>(ei, gcount, epk);
    k_rank <<<NBUCK, 512, 0, stream>>>(epk, gcount, offs, ssrc);
    k_bound<<<(N_NODES + 255) / 256, 256, 0, stream>>>(batch, gstart);
    k_packbf <<<64, 256, 0, stream>>>(W2l, W2r, Wcat);
    k_packbf1<<<16, 256, 0, stream>>>(W1l, W1r, Wcat1);

    // layer 1 (bf16 + MFMA; stats fused into k_lin1)
    k_agg1  <<<(N_NODES + 255) / 256, 256, 0, stream>>>(x, offs, ssrc, xa);
    k_lin1  <<<(N_NODES + 63) / 64, 256, 0, stream>>>(xa, Wcat1, b1, h1bf, stats);
    k_bnfin <<<1, 128, 0, stream>>>(stats, g1, be1, scsh);
    k_bnrelu<<<(N_NODES * F / 8) / 256, 256, 0, stream>>>(h1bf, scsh, x1bf);

    // layer 2 (bf16 + MFMA; stats fused into k_lin2)
    k_agg2  <<<N_NODES / 16, 256, 0, stream>>>(x1bf, offs, ssrc, agg2bf);
    k_lin2  <<<(N_NODES + 127) / 128, 256, 0, stream>>>(agg2bf, x1bf, Wcat, b2,
                                                        h2bf, stats + 256);
    k_bnfin <<<1, 128, 0, stream>>>(stats + 256, g2, be2, scsh + 256);

    // residual + pool
    k_pool<<<(N_NODES + 127) / 128, 128, 0, stream>>>(x1bf, h2bf, scsh + 256, batch, outacc);
    k_out <<<(NUM_GRAPHS * F + 255) / 256, 256, 0, stream>>>(outacc, gstart, out);
}

// Round 6
// 490.624 us; speedup vs baseline: 1.7751x; 1.0003x over previous
//
#include <hip/hip_runtime.h>
#include <cstdint>
#include <cstddef>

namespace {

constexpr int N_NODES = 100000;
constexpr int N_EDGES = 1600000;
constexpr int NUM_GRAPHS = 128;
constexpr int F = 128;
constexpr float BN_EPS = 1e-5f;

// bucket sort params: 196 buckets x 512 nodes; 400 chunks x 4000 edges
constexpr int W_BUCK = 512;
constexpr int NBUCK = (N_NODES + W_BUCK - 1) / W_BUCK;  // 196
constexpr int CB = 400;
constexpr int CHUNK = N_EDGES / CB;                      // 4000

typedef float f32x4 __attribute__((ext_vector_type(4)));
typedef short s16x8 __attribute__((ext_vector_type(8)));
union B8 { uint4 u; s16x8 s; };

__device__ inline ushort f2bf(float x) {         // RNE fp32 -> bf16
    uint u = __float_as_uint(x);
    u += 0x7fffu + ((u >> 16) & 1u);
    return (ushort)(u >> 16);
}
__device__ inline float bf2f(ushort s) { return __uint_as_float(((uint)s) << 16); }
__device__ inline uint pack2(float lo, float hi) {
    return (uint)f2bf(lo) | ((uint)f2bf(hi) << 16);
}
__device__ inline float bflo(uint u) { return __uint_as_float(u << 16); }
__device__ inline float bfhi(uint u) { return __uint_as_float(u & 0xffff0000u); }

// ---- CSR-by-dst via 2-level bucket sort (no global atomics) -----------------

// per-chunk bucket histogram (LDS only)
__global__ void __launch_bounds__(256) k_histA(const int* __restrict__ ei,
                                               int* __restrict__ gcount) {
    __shared__ int bins[NBUCK];
    int t = threadIdx.x;
    for (int i = t; i < NBUCK; i += 256) bins[i] = 0;
    __syncthreads();
    int e0 = blockIdx.x * CHUNK;
    for (int i = t; i < CHUNK; i += 256)
        atomicAdd(&bins[ei[N_EDGES + e0 + i] >> 9], 1);
    __syncthreads();
    for (int i = t; i < NBUCK; i += 256) gcount[i * CB + blockIdx.x] = bins[i];
}

// single-block in-place exclusive scan of gcount (NBUCK*CB ints)
__global__ void __launch_bounds__(1024) k_scanG(int* __restrict__ g, int n) {
    __shared__ int ts[1024];
    int t = threadIdx.x;
    int per = (n + 1023) / 1024;
    int lo = t * per, hi = min(lo + per, n);
    int s = 0;
    for (int i = lo; i < hi; ++i) s += g[i];
    ts[t] = s;
    __syncthreads();
    #pragma unroll
    for (int d = 1; d < 1024; d <<= 1) {
        int v = (t >= d) ? ts[t - d] : 0;
        __syncthreads();
        ts[t] += v;
        __syncthreads();
    }
    int run = ts[t] - s;
    for (int i = lo; i < hi; ++i) {
        int v = g[i];
        g[i] = run;
        run += v;
    }
}

// partition edges into bucket runs; packed u32 = (src<<9)|(dst&511)
__global__ void __launch_bounds__(256) k_part(const int* __restrict__ ei,
                                              const int* __restrict__ goffs,
                                              uint* __restrict__ epk) {
    __shared__ int cur[NBUCK];
    int t = threadIdx.x;
    for (int i = t; i < NBUCK; i += 256) cur[i] = goffs[i * CB + blockIdx.x];
    __syncthreads();
    int e0 = blockIdx.x * CHUNK;
    for (int i = t; i < CHUNK; i += 256) {
        int d = ei[N_EDGES + e0 + i];
        int s = ei[e0 + i];
        int p = atomicAdd(&cur[d >> 9], 1);
        epk[p] = ((uint)s << 9) | (uint)(d & 511);
    }
}

// per-bucket: LDS degree hist -> LDS scan -> offs (non-atomic) -> counting sort
__global__ void __launch_bounds__(512) k_rank(const uint* __restrict__ epk,
                                              const int* __restrict__ goffs,
                                              int* __restrict__ offs,
                                              int* __restrict__ ssrc) {
    __shared__ int dcnt[W_BUCK];
    __shared__ int tmp[W_BUCK];
    __shared__ int cur[W_BUCK];
    int b = blockIdx.x, t = threadIdx.x;
    dcnt[t] = 0;
    __syncthreads();
    int s0 = goffs[b * CB];
    int s1 = (b + 1 < NBUCK) ? goffs[(b + 1) * CB] : N_EDGES;
    for (int i = s0 + t; i < s1; i += 512)
        atomicAdd(&dcnt[epk[i] & 511u], 1);
    __syncthreads();
    int v = dcnt[t];
    tmp[t] = v;
    __syncthreads();
    #pragma unroll
    for (int d = 1; d < 512; d <<= 1) {
        int u = (t >= d) ? tmp[t - d] : 0;
        __syncthreads();
        tmp[t] += u;
        __syncthreads();
    }
    int start = s0 + tmp[t] - v;               // exclusive prefix
    int node = b * W_BUCK + t;
    if (node <= N_NODES) offs[node] = start;   // node==N_NODES: writes offs end
    cur[t] = start;
    __syncthreads();
    for (int i = s0 + t; i < s1; i += 512) {
        uint u = epk[i];
        int p = atomicAdd(&cur[u & 511u], 1);
        ssrc[p] = (int)(u >> 9);
    }
}

// ---- graph segment boundaries (batch is sorted) ----------------------------

__global__ void k_bound(const int* __restrict__ batch, int* __restrict__ gstart) {
    int i = blockIdx.x * 256 + threadIdx.x;
    if (i >= N_NODES) return;
    int b = batch[i];
    if (i == 0) {
        for (int g = 0; g <= b; ++g) gstart[g] = 0;
    } else {
        int p = batch[i - 1];
        if (p != b) for (int g = p + 1; g <= b; ++g) gstart[g] = i;
    }
    if (i == N_NODES - 1) {
        for (int g = b + 1; g <= NUM_GRAPHS; ++g) gstart[g] = N_NODES;
    }
}

// ---- weight packs -----------------------------------------------------------

// layer 2: Wcat[f][0:128]=W2l[f][:], Wcat[f][128:256]=W2r[f][:], bf16
__global__ void k_packbf(const float* __restrict__ Wl, const float* __restrict__ Wr,
                         ushort* __restrict__ Wcat) {
    int i = blockIdx.x * 256 + threadIdx.x;    // 16384 exact
    int f = i >> 7, k = i & 127;
    Wcat[f * 256 + k]       = f2bf(Wl[i]);
    Wcat[f * 256 + 128 + k] = f2bf(Wr[i]);
}

// layer 1: Wcat1[f][32] bf16: k<8 -> W1r[f][k], 8..15 -> W1l[f][k-8], rest 0
__global__ void k_packbf1(const float* __restrict__ W1l, const float* __restrict__ W1r,
                          ushort* __restrict__ Wcat1) {
    int i = blockIdx.x * 256 + threadIdx.x;    // 4096 exact
    int f = i >> 5, k = i & 31;
    float v = (k < 8) ? W1r[f * 8 + k] : ((k < 16) ? W1l[f * 8 + (k - 8)] : 0.f);
    Wcat1[i] = f2bf(v);
}

// ---- layer 1 ---------------------------------------------------------------

// xa[n][32] bf16 = [x[n] (8) | mean_j x[src] (8) | zeros (16)]  — one 64B line
__global__ void k_agg1(const float* __restrict__ x, const int* __restrict__ offs,
                       const int* __restrict__ ssrc, ushort* __restrict__ xa) {
    int n = blockIdx.x * 256 + threadIdx.x;
    if (n >= N_NODES) return;
    int s0 = offs[n], s1 = offs[n + 1];
    float a0=0,a1=0,a2=0,a3=0,a4=0,a5=0,a6=0,a7=0;
    int j = s0;
    for (; j + 3 < s1; j += 4) {               // 8 gathers in flight
        int sa = ssrc[j], sb = ssrc[j+1], sc = ssrc[j+2], sd = ssrc[j+3];
        const float4* pa = (const float4*)(x + (size_t)sa * 8);
        const float4* pb = (const float4*)(x + (size_t)sb * 8);
        const float4* pc = (const float4*)(x + (size_t)sc * 8);
        const float4* pd = (const float4*)(x + (size_t)sd * 8);
        float4 va0 = pa[0], va1 = pa[1], vb0 = pb[0], vb1 = pb[1];
        float4 vc0 = pc[0], vc1 = pc[1], vd0 = pd[0], vd1 = pd[1];
        a0 += (va0.x + vb0.x) + (vc0.x + vd0.x);
        a1 += (va0.y + vb0.y) + (vc0.y + vd0.y);
        a2 += (va0.z + vb0.z) + (vc0.z + vd0.z);
        a3 += (va0.w + vb0.w) + (vc0.w + vd0.w);
        a4 += (va1.x + vb1.x) + (vc1.x + vd1.x);
        a5 += (va1.y + vb1.y) + (vc1.y + vd1.y);
        a6 += (va1.z + vb1.z) + (vc1.z + vd1.z);
        a7 += (va1.w + vb1.w) + (vc1.w + vd1.w);
    }
    for (; j < s1; ++j) {
        const float4* xp = (const float4*)(x + (size_t)ssrc[j] * 8);
        float4 b0 = xp[0], b1 = xp[1];
        a0+=b0.x; a1+=b0.y; a2+=b0.z; a3+=b0.w;
        a4+=b1.x; a5+=b1.y; a6+=b1.z; a7+=b1.w;
    }
    int dg = s1 - s0;
    float inv = 1.0f / (float)(dg > 1 ? dg : 1);
    const float4* xp = (const float4*)(x + (size_t)n * 8);
    float4 x0 = xp[0], x1v = xp[1];
    ushort* row = xa + (size_t)n * 32;
    uint4 o0 = {pack2(x0.x, x0.y), pack2(x0.z, x0.w), pack2(x1v.x, x1v.y), pack2(x1v.z, x1v.w)};
    uint4 o1 = {pack2(a0*inv, a1*inv), pack2(a2*inv, a3*inv),
                pack2(a4*inv, a5*inv), pack2(a6*inv, a7*inv)};
    uint4 z = {0u, 0u, 0u, 0u};
    *(uint4*)(row)      = o0;
    *(uint4*)(row + 8)  = o1;
    *(uint4*)(row + 16) = z;
    *(uint4*)(row + 24) = z;
}

// h1bf = bf16(xa @ Wcat1^T + b1) via one MFMA per f-tile; fp32 BN stats fused.
__global__ void __launch_bounds__(256) k_lin1(
        const ushort* __restrict__ xa, const ushort* __restrict__ Wcat1,
        const float* __restrict__ b1, ushort* __restrict__ h1bf,
        float* __restrict__ stats) {
    __shared__ ushort sOut[64 * 140];          // stride 140: 4-quad conflict-free
    __shared__ float sred[256];
    int tid = threadIdx.x;
    int wave = tid >> 6, lane = tid & 63;
    int quad = lane >> 4, l16 = lane & 15;
    int n0 = blockIdx.x * 64;

    int node = n0 + wave * 16 + l16;
    int cn = (node < N_NODES) ? node : N_NODES - 1;  // clamp; stores masked below
    B8 ta;
    ta.u = *(const uint4*)(xa + (size_t)cn * 32 + quad * 8);

    #pragma unroll
    for (int nt = 0; nt < 8; ++nt) {
        int fb = nt * 16 + l16;
        B8 tb;
        tb.u = *(const uint4*)(Wcat1 + fb * 32 + quad * 8);
        f32x4 acc = {0.f, 0.f, 0.f, 0.f};
        acc = __builtin_amdgcn_mfma_f32_16x16x32_bf16(ta.s, tb.s, acc, 0, 0, 0);
        float bb = b1[fb];
        #pragma unroll
        for (int r = 0; r < 4; ++r) {
            int row = wave * 16 + quad * 4 + r;
            sOut[row * 140 + fb] = f2bf(acc[r] + bb);
        }
    }
    __syncthreads();

    #pragma unroll
    for (int p = 0; p < 4; ++p) {
        int row = p * 16 + (tid >> 4);
        int nd = n0 + row;
        if (nd < N_NODES) {
            int c0 = (tid & 15) * 8;
            uint4 v = *(const uint4*)&sOut[row * 140 + c0];
            *(uint4*)(h1bf + (size_t)nd * F + c0) = v;
        }
    }

    int f = tid & 127, half = tid >> 7;
    float s = 0.f, s2 = 0.f;
    for (int r = half * 32; r < half * 32 + 32; ++r) {
        if (n0 + r >= N_NODES) break;
        float v = bf2f(sOut[r * 140 + f]);
        s += v; s2 += v * v;
    }
    if (half) { sred[f] = s; sred[128 + f] = s2; }
    __syncthreads();
    if (!half) {
        s += sred[f]; s2 += sred[128 + f];
        atomicAdd(&stats[f], s);
        atomicAdd(&stats[F + f], s2);
    }
}

__global__ void k_bnfin(const float* __restrict__ stats, const float* __restrict__ gamma,
                        const float* __restrict__ beta, float* __restrict__ scsh) {
    int f = threadIdx.x;
    float mu  = stats[f] * (1.0f / N_NODES);
    float var = stats[F + f] * (1.0f / N_NODES) - mu * mu;
    float sc  = gamma[f] * rsqrtf(var + BN_EPS);
    scsh[f] = sc;
    scsh[F + f] = beta[f] - mu * sc;
}

// x1bf = bf16(relu(scale*h1 + shift))
__global__ void k_bnrelu(const ushort* __restrict__ h, const float* __restrict__ scsh,
                         ushort* __restrict__ x1bf) {
    int i = blockIdx.x * 256 + threadIdx.x;      // N*128/8 = 1.6M exact
    int base = i * 8;
    int f = base & (F - 1);
    float4 sc0 = *(const float4*)(scsh + f);
    float4 sc1 = *(const float4*)(scsh + f + 4);
    float4 sh0 = *(const float4*)(scsh + F + f);
    float4 sh1 = *(const float4*)(scsh + F + f + 4);
    uint4 hv = *(const uint4*)(h + base);
    float v0 = fmaxf(0.f, bflo(hv.x)*sc0.x + sh0.x);
    float v1 = fmaxf(0.f, bfhi(hv.x)*sc0.y + sh0.y);
    float v2 = fmaxf(0.f, bflo(hv.y)*sc0.z + sh0.z);
    float v3 = fmaxf(0.f, bfhi(hv.y)*sc0.w + sh0.w);
    float v4 = fmaxf(0.f, bflo(hv.z)*sc1.x + sh1.x);
    float v5 = fmaxf(0.f, bfhi(hv.z)*sc1.y + sh1.y);
    float v6 = fmaxf(0.f, bflo(hv.w)*sc1.z + sh1.z);
    float v7 = fmaxf(0.f, bfhi(hv.w)*sc1.w + sh1.w);
    uint4 o = {pack2(v0,v1), pack2(v2,v3), pack2(v4,v5), pack2(v6,v7)};
    *(uint4*)(x1bf + base) = o;
}

// ---- layer 2 ---------------------------------------------------------------

// agg2bf[n][f] = bf16(mean over in-edges of x1bf[src][f]); 16 threads x 16B/node
__global__ void __launch_bounds__(256) k_agg2(
        const ushort* __restrict__ x1bf, const int* __restrict__ offs,
        const int* __restrict__ ssrc, ushort* __restrict__ agg2bf) {
    int t = threadIdx.x;
    int n = blockIdx.x * 16 + (t >> 4);
    int c8 = (t & 15) * 8;
    int s0 = offs[n], s1 = offs[n + 1];
    float acc[8] = {0,0,0,0,0,0,0,0};
    int j = s0;
    for (; j + 3 < s1; j += 4) {               // 4 gathers in flight
        int sa = ssrc[j], sb = ssrc[j+1], sc = ssrc[j+2], sd = ssrc[j+3];
        uint4 va = *(const uint4*)(x1bf + (size_t)sa * F + c8);
        uint4 vb = *(const uint4*)(x1bf + (size_t)sb * F + c8);
        uint4 vc = *(const uint4*)(x1bf + (size_t)sc * F + c8);
        uint4 vd = *(const uint4*)(x1bf + (size_t)sd * F + c8);
        acc[0] += (bflo(va.x)+bflo(vb.x)) + (bflo(vc.x)+bflo(vd.x));
        acc[1] += (bfhi(va.x)+bfhi(vb.x)) + (bfhi(vc.x)+bfhi(vd.x));
        acc[2] += (bflo(va.y)+bflo(vb.y)) + (bflo(vc.y)+bflo(vd.y));
        acc[3] += (bfhi(va.y)+bfhi(vb.y)) + (bfhi(vc.y)+bfhi(vd.y));
        acc[4] += (bflo(va.z)+bflo(vb.z)) + (bflo(vc.z)+bflo(vd.z));
        acc[5] += (bfhi(va.z)+bfhi(vb.z)) + (bfhi(vc.z)+bfhi(vd.z));
        acc[6] += (bflo(va.w)+bflo(vb.w)) + (bflo(vc.w)+bflo(vd.w));
        acc[7] += (bfhi(va.w)+bfhi(vb.w)) + (bfhi(vc.w)+bfhi(vd.w));
    }
    for (; j < s1; ++j) {
        uint4 v = *(const uint4*)(x1bf + (size_t)ssrc[j] * F + c8);
        acc[0] += bflo(v.x); acc[1] += bfhi(v.x);
        acc[2] += bflo(v.y); acc[3] += bfhi(v.y);
        acc[4] += bflo(v.z); acc[5] += bfhi(v.z);
        acc[6] += bflo(v.w); acc[7] += bfhi(v.w);
    }
    int dg = s1 - s0;
    float inv = 1.0f / (float)(dg > 1 ? dg : 1);
    uint4 o = {pack2(acc[0]*inv, acc[1]*inv), pack2(acc[2]*inv, acc[3]*inv),
               pack2(acc[4]*inv, acc[5]*inv), pack2(acc[6]*inv, acc[7]*inv)};
    *(uint4*)(agg2bf + (size_t)n * F + c8) = o;
}

// h2 = agg2 @ W2l^T + b2 + x1 @ W2r^T via bf16 MFMA; BN stats fused.
__global__ void __launch_bounds__(256) k_lin2(
        const ushort* __restrict__ agg2bf, const ushort* __restrict__ x1bf,
        const ushort* __restrict__ Wcat, const float* __restrict__ b2,
        ushort* __restrict__ h2bf, float* __restrict__ stats) {
    __shared__ ushort sOut[128 * 136];         // 128x128 bf16 tile, stride 136
    __shared__ float sred[256];
    int tid = threadIdx.x;
    int wave = tid >> 6, lane = tid & 63;
    int quad = lane >> 4, l16 = lane & 15;
    int n0 = blockIdx.x * 128 + wave * 32;

    s16x8 a[2][8];
    #pragma unroll
    for (int mt = 0; mt < 2; ++mt) {
        int node = n0 + mt * 16 + l16;
        if (node >= N_NODES) node = N_NODES - 1;   // clamp; stores masked below
        #pragma unroll
        for (int ks = 0; ks < 8; ++ks) {
            const ushort* src = (ks < 4) ? agg2bf : x1bf;
            B8 tm;
            tm.u = *(const uint4*)(src + (size_t)node * F + (ks & 3) * 32 + quad * 8);
            a[mt][ks] = tm.s;
        }
    }

    #pragma unroll
    for (int nt = 0; nt < 8; ++nt) {
        int fb = nt * 16 + l16;
        s16x8 b[8];
        #pragma unroll
        for (int ks = 0; ks < 8; ++ks) {
            B8 tm;
            tm.u = *(const uint4*)(Wcat + fb * 256 + ks * 32 + quad * 8);
            b[ks] = tm.s;
        }
        f32x4 acc0 = {0.f, 0.f, 0.f, 0.f};
        f32x4 acc1 = {0.f, 0.f, 0.f, 0.f};
        #pragma unroll
        for (int ks = 0; ks < 8; ++ks) {
            acc0 = __builtin_amdgcn_mfma_f32_16x16x32_bf16(a[0][ks], b[ks], acc0, 0, 0, 0);
            acc1 = __builtin_amdgcn_mfma_f32_16x16x32_bf16(a[1][ks], b[ks], acc1, 0, 0, 0);
        }
        float bb = b2[fb];
        #pragma unroll
        for (int r = 0; r < 4; ++r) {
            int row0 = wave * 32 + quad * 4 + r;          // mt = 0
            sOut[row0 * 136 + fb]        = f2bf(acc0[r] + bb);
            sOut[(row0 + 16) * 136 + fb] = f2bf(acc1[r] + bb);
        }
    }
    __syncthreads();

    #pragma unroll
    for (int p = 0; p < 8; ++p) {
        int row = p * 16 + (tid >> 4);
        int node = blockIdx.x * 128 + row;
        if (node < N_NODES) {
            int c0 = (tid & 15) * 8;
            uint4 v = *(const uint4*)&sOut[row * 136 + c0];
            *(uint4*)(h2bf + (size_t)node * F + c0) = v;
        }
    }

    int f = tid & 127, half = tid >> 7;
    float s = 0.f, s2 = 0.f;
    for (int r = half * 64; r < half * 64 + 64; ++r) {
        int node = blockIdx.x * 128 + r;
        if (node >= N_NODES) break;
        float v = bf2f(sOut[r * 136 + f]);
        s += v; s2 += v * v;
    }
    if (half) { sred[f] = s; sred[128 + f] = s2; }
    __syncthreads();
    if (!half) {
        s += sred[f]; s2 += sred[128 + f];
        atomicAdd(&stats[f], s);
        atomicAdd(&stats[F + f], s2);
    }
}

// ---- pooling ---------------------------------------------------------------

__global__ void k_pool(const ushort* __restrict__ x1bf, const ushort* __restrict__ h2bf,
                       const float* __restrict__ scsh2, const int* __restrict__ batch,
                       float* __restrict__ outacc) {
    int f = threadIdx.x;
    int n0 = blockIdx.x * 128;
    int n1 = min(n0 + 128, N_NODES);
    float sc = scsh2[f], sh = scsh2[F + f];
    float acc = 0.f;
    int curg = batch[n0];
    for (int n = n0; n < n1; ++n) {
        int g = batch[n];
        if (g != curg) {
            atomicAdd(&outacc[curg * F + f], acc);
            acc = 0.f; curg = g;
        }
        float v1 = bf2f(x1bf[(size_t)n * F + f]);
        float v2 = fmaxf(0.f, bf2f(h2bf[(size_t)n * F + f]) * sc + sh);
        acc += v1 + v2;
    }
    atomicAdd(&outacc[curg * F + f], acc);
}

__global__ void k_out(const float* __restrict__ outacc, const int* __restrict__ gstart,
                      float* __restrict__ out) {
    int i = blockIdx.x * 256 + threadIdx.x;
    if (i >= NUM_GRAPHS * F) return;
    int g = i >> 7;
    int c = gstart[g + 1] - gstart[g];
    out[i] = outacc[i] / (float)(c > 1 ? c : 1);
}

}  // namespace

extern "C" void kernel_launch(void* const* d_in, const int* in_sizes, int n_in,
                              void* d_out, int out_size, void* d_ws, size_t ws_size,
                              hipStream_t stream) {
    const float* x     = (const float*)d_in[0];
    const int*   ei    = (const int*)d_in[1];    // [2, E]: row0 = src, row1 = dst
    const int*   batch = (const int*)d_in[2];
    const float* W1l   = (const float*)d_in[3];
    const float* b1    = (const float*)d_in[4];
    const float* W1r   = (const float*)d_in[5];
    const float* g1    = (const float*)d_in[6];
    const float* be1   = (const float*)d_in[7];
    const float* W2l   = (const float*)d_in[8];
    const float* b2    = (const float*)d_in[9];
    const float* W2r   = (const float*)d_in[10];
    const float* g2    = (const float*)d_in[11];
    const float* be2   = (const float*)d_in[12];
    float* out = (float*)d_out;

    char* w = (char*)d_ws;
    size_t o = 0;
    auto alloc = [&](size_t bytes) {
        void* p = w + o;
        o += (bytes + 511) & ~(size_t)511;
        return p;
    };
    int*    offs   = (int*)alloc((size_t)(N_NODES + 1) * 4);
    int*    gcount = (int*)alloc((size_t)NBUCK * CB * 4);
    int*    ssrc   = (int*)alloc((size_t)N_EDGES * 4);
    uint*   epk    = (uint*)alloc((size_t)N_EDGES * 4);
    int*    gstart = (int*)alloc((NUM_GRAPHS + 1) * 4);
    float*  stats  = (float*)alloc(512 * 4);   // [s1,s1sq | s2,s2sq]
    float*  scsh   = (float*)alloc(512 * 4);   // [sc1,sh1 | sc2,sh2]
    ushort* Wcat   = (ushort*)alloc((size_t)F * 256 * 2);
    ushort* Wcat1  = (ushort*)alloc((size_t)F * 32 * 2);
    float*  outacc = (float*)alloc((size_t)NUM_GRAPHS * F * 4);
    ushort* xa     = (ushort*)alloc((size_t)N_NODES * 32 * 2);
    ushort* h1bf   = (ushort*)alloc((size_t)N_NODES * F * 2);
    ushort* x1bf   = (ushort*)alloc((size_t)N_NODES * F * 2);
    ushort* agg2bf = (ushort*)alloc((size_t)N_NODES * F * 2);
    ushort* h2bf   = (ushort*)alloc((size_t)N_NODES * F * 2);

    hipMemsetAsync(stats,  0, 512 * 4, stream);
    hipMemsetAsync(outacc, 0, (size_t)NUM_GRAPHS * F * 4, stream);

    // CSR-by-dst: chunk bucket hist -> scan -> partition -> per-bucket rank
    k_histA<<<CB, 256, 0, stream>>>(ei, gcount);
    k_scanG<<<1, 1024, 0, stream>>>(gcount, NBUCK * CB);
    k_part <<<CB, 256, 0, stream>>>(ei, gcount, epk);
    k_rank <<<NBUCK, 512, 0, stream>>>(epk, gcount, offs, ssrc);
    k_bound<<<(N_NODES + 255) / 256, 256, 0, stream>>>(batch, gstart);
    k_packbf <<<64, 256, 0, stream>>>(W2l, W2r, Wcat);
    k_packbf1<<<16, 256, 0, stream>>>(W1l, W1r, Wcat1);

    // layer 1 (bf16 + MFMA; stats fused into k_lin1)
    k_agg1  <<<(N_NODES + 255) / 256, 256, 0, stream>>>(x, offs, ssrc, xa);
    k_lin1  <<<(N_NODES + 63) / 64, 256, 0, stream>>>(xa, Wcat1, b1, h1bf, stats);
    k_bnfin <<<1, 128, 0, stream>>>(stats, g1, be1, scsh);
    k_bnrelu<<<(N_NODES * F / 8) / 256, 256, 0, stream>>>(h1bf, scsh, x1bf);

    // layer 2 (bf16 + MFMA; stats fused into k_lin2)
    k_agg2  <<<N_NODES / 16, 256, 0, stream>>>(x1bf, offs, ssrc, agg2bf);
    k_lin2  <<<(N_NODES + 127) / 128, 256, 0, stream>>>(agg2bf, x1bf, Wcat, b2,
                                                        h2bf, stats + 256);
    k_bnfin <<<1, 128, 0, stream>>>(stats + 256, g2, be2, scsh + 256);

    // residual + pool
    k_pool<<<(N_NODES + 127) / 128, 128, 0, stream>>>(x1bf, h2bf, scsh + 256, batch, outacc);
    k_out <<<(NUM_GRAPHS * F + 255) / 256, 256, 0, stream>>>(outacc, gstart, out);
}

// Round 7
// 369.810 us; speedup vs baseline: 2.3550x; 1.3267x over previous
//
#include <hip/hip_runtime.h>
#include <cstdint>
#include <cstddef>

namespace {

constexpr int N_NODES = 100000;
constexpr int N_EDGES = 1600000;
constexpr int NUM_GRAPHS = 128;
constexpr int F = 128;
constexpr float BN_EPS = 1e-5f;

// bucket sort params: 196 buckets x 512 nodes; 400 chunks x 4000 edges
constexpr int W_BUCK = 512;
constexpr int NBUCK = (N_NODES + W_BUCK - 1) / W_BUCK;  // 196
constexpr int CB = 400;
constexpr int CHUNK = N_EDGES / CB;                      // 4000

typedef float f32x4 __attribute__((ext_vector_type(4)));
typedef short s16x8 __attribute__((ext_vector_type(8)));
union B8 { uint4 u; s16x8 s; };

__device__ inline ushort f2bf(float x) {         // RNE fp32 -> bf16
    uint u = __float_as_uint(x);
    u += 0x7fffu + ((u >> 16) & 1u);
    return (ushort)(u >> 16);
}
__device__ inline float bf2f(ushort s) { return __uint_as_float(((uint)s) << 16); }
__device__ inline uint pack2(float lo, float hi) {
    return (uint)f2bf(lo) | ((uint)f2bf(hi) << 16);
}
__device__ inline float bflo(uint u) { return __uint_as_float(u << 16); }
__device__ inline float bfhi(uint u) { return __uint_as_float(u & 0xffff0000u); }

// ---- CSR-by-dst via 2-level bucket sort (no global atomics) -----------------

// per-chunk bucket histogram (LDS only)
__global__ void __launch_bounds__(256) k_histA(const int* __restrict__ ei,
                                               int* __restrict__ gcount) {
    __shared__ int bins[NBUCK];
    int t = threadIdx.x;
    for (int i = t; i < NBUCK; i += 256) bins[i] = 0;
    __syncthreads();
    int e0 = blockIdx.x * CHUNK;
    for (int i = t; i < CHUNK; i += 256)
        atomicAdd(&bins[ei[N_EDGES + e0 + i] >> 9], 1);
    __syncthreads();
    for (int i = t; i < NBUCK; i += 256) gcount[i * CB + blockIdx.x] = bins[i];
}

// per-bucket local exclusive scan of the CB chunk-counts + bucket total
__global__ void __launch_bounds__(512) k_scanA(int* __restrict__ g,
                                               int* __restrict__ bsum) {
    __shared__ int tmp[512];
    int b = blockIdx.x, t = threadIdx.x;
    int v = (t < CB) ? g[b * CB + t] : 0;
    tmp[t] = v;
    __syncthreads();
    #pragma unroll
    for (int d = 1; d < 512; d <<= 1) {
        int u = (t >= d) ? tmp[t - d] : 0;
        __syncthreads();
        tmp[t] += u;
        __syncthreads();
    }
    if (t < CB) g[b * CB + t] = tmp[t] - v;   // local exclusive prefix
    if (t == 511) bsum[b] = tmp[511];         // bucket total
}

// exclusive scan of the NBUCK bucket totals (tiny, one block)
__global__ void __launch_bounds__(256) k_scanB(int* __restrict__ bsum) {
    __shared__ int tmp[256];
    int t = threadIdx.x;
    int v = (t < NBUCK) ? bsum[t] : 0;
    tmp[t] = v;
    __syncthreads();
    #pragma unroll
    for (int d = 1; d < 256; d <<= 1) {
        int u = (t >= d) ? tmp[t - d] : 0;
        __syncthreads();
        tmp[t] += u;
        __syncthreads();
    }
    if (t < NBUCK) bsum[t] = tmp[t] - v;      // bucket exclusive prefix
}

// partition edges into bucket runs; packed u32 = (src<<9)|(dst&511)
__global__ void __launch_bounds__(256) k_part(const int* __restrict__ ei,
                                              const int* __restrict__ gloc,
                                              const int* __restrict__ bsum,
                                              uint* __restrict__ epk) {
    __shared__ int cur[NBUCK];
    int t = threadIdx.x;
    for (int i = t; i < NBUCK; i += 256)
        cur[i] = gloc[i * CB + blockIdx.x] + bsum[i];
    __syncthreads();
    int e0 = blockIdx.x * CHUNK;
    for (int i = t; i < CHUNK; i += 256) {
        int d = ei[N_EDGES + e0 + i];
        int s = ei[e0 + i];
        int p = atomicAdd(&cur[d >> 9], 1);
        epk[p] = ((uint)s << 9) | (uint)(d & 511);
    }
}

// per-bucket: LDS degree hist -> LDS scan -> offs (non-atomic) -> counting sort
__global__ void __launch_bounds__(512) k_rank(const uint* __restrict__ epk,
                                              const int* __restrict__ bsum,
                                              int* __restrict__ offs,
                                              int* __restrict__ ssrc) {
    __shared__ int dcnt[W_BUCK];
    __shared__ int tmp[W_BUCK];
    __shared__ int cur[W_BUCK];
    int b = blockIdx.x, t = threadIdx.x;
    dcnt[t] = 0;
    __syncthreads();
    int s0 = bsum[b];
    int s1 = (b + 1 < NBUCK) ? bsum[b + 1] : N_EDGES;
    for (int i = s0 + t; i < s1; i += 512)
        atomicAdd(&dcnt[epk[i] & 511u], 1);
    __syncthreads();
    int v = dcnt[t];
    tmp[t] = v;
    __syncthreads();
    #pragma unroll
    for (int d = 1; d < 512; d <<= 1) {
        int u = (t >= d) ? tmp[t - d] : 0;
        __syncthreads();
        tmp[t] += u;
        __syncthreads();
    }
    int start = s0 + tmp[t] - v;               // exclusive prefix
    int node = b * W_BUCK + t;
    if (node <= N_NODES) offs[node] = start;   // node==N_NODES: writes offs end
    cur[t] = start;
    __syncthreads();
    for (int i = s0 + t; i < s1; i += 512) {
        uint u = epk[i];
        int p = atomicAdd(&cur[u & 511u], 1);
        ssrc[p] = (int)(u >> 9);
    }
}

// ---- graph segment boundaries (batch is sorted) ----------------------------

__global__ void k_bound(const int* __restrict__ batch, int* __restrict__ gstart) {
    int i = blockIdx.x * 256 + threadIdx.x;
    if (i >= N_NODES) return;
    int b = batch[i];
    if (i == 0) {
        for (int g = 0; g <= b; ++g) gstart[g] = 0;
    } else {
        int p = batch[i - 1];
        if (p != b) for (int g = p + 1; g <= b; ++g) gstart[g] = i;
    }
    if (i == N_NODES - 1) {
        for (int g = b + 1; g <= NUM_GRAPHS; ++g) gstart[g] = N_NODES;
    }
}

// ---- weight packs -----------------------------------------------------------

// layer 2: Wcat[f][0:128]=W2l[f][:], Wcat[f][128:256]=W2r[f][:], bf16
__global__ void k_packbf(const float* __restrict__ Wl, const float* __restrict__ Wr,
                         ushort* __restrict__ Wcat) {
    int i = blockIdx.x * 256 + threadIdx.x;    // 16384 exact
    int f = i >> 7, k = i & 127;
    Wcat[f * 256 + k]       = f2bf(Wl[i]);
    Wcat[f * 256 + 128 + k] = f2bf(Wr[i]);
}

// layer 1: Wcat1[f][32] bf16: k<8 -> W1r[f][k], 8..15 -> W1l[f][k-8], rest 0
__global__ void k_packbf1(const float* __restrict__ W1l, const float* __restrict__ W1r,
                          ushort* __restrict__ Wcat1) {
    int i = blockIdx.x * 256 + threadIdx.x;    // 4096 exact
    int f = i >> 5, k = i & 31;
    float v = (k < 8) ? W1r[f * 8 + k] : ((k < 16) ? W1l[f * 8 + (k - 8)] : 0.f);
    Wcat1[i] = f2bf(v);
}

// ---- layer 1 ---------------------------------------------------------------

// xa[n][32] bf16 = [x[n] (8) | mean_j x[src] (8) | zeros (16)]  — one 64B line
__global__ void k_agg1(const float* __restrict__ x, const int* __restrict__ offs,
                       const int* __restrict__ ssrc, ushort* __restrict__ xa) {
    int n = blockIdx.x * 256 + threadIdx.x;
    if (n >= N_NODES) return;
    int s0 = offs[n], s1 = offs[n + 1];
    float a0=0,a1=0,a2=0,a3=0,a4=0,a5=0,a6=0,a7=0;
    int j = s0;
    for (; j + 3 < s1; j += 4) {               // 8 gathers in flight
        int sa = ssrc[j], sb = ssrc[j+1], sc = ssrc[j+2], sd = ssrc[j+3];
        const float4* pa = (const float4*)(x + (size_t)sa * 8);
        const float4* pb = (const float4*)(x + (size_t)sb * 8);
        const float4* pc = (const float4*)(x + (size_t)sc * 8);
        const float4* pd = (const float4*)(x + (size_t)sd * 8);
        float4 va0 = pa[0], va1 = pa[1], vb0 = pb[0], vb1 = pb[1];
        float4 vc0 = pc[0], vc1 = pc[1], vd0 = pd[0], vd1 = pd[1];
        a0 += (va0.x + vb0.x) + (vc0.x + vd0.x);
        a1 += (va0.y + vb0.y) + (vc0.y + vd0.y);
        a2 += (va0.z + vb0.z) + (vc0.z + vd0.z);
        a3 += (va0.w + vb0.w) + (vc0.w + vd0.w);
        a4 += (va1.x + vb1.x) + (vc1.x + vd1.x);
        a5 += (va1.y + vb1.y) + (vc1.y + vd1.y);
        a6 += (va1.z + vb1.z) + (vc1.z + vd1.z);
        a7 += (va1.w + vb1.w) + (vc1.w + vd1.w);
    }
    for (; j < s1; ++j) {
        const float4* xp = (const float4*)(x + (size_t)ssrc[j] * 8);
        float4 b0 = xp[0], b1 = xp[1];
        a0+=b0.x; a1+=b0.y; a2+=b0.z; a3+=b0.w;
        a4+=b1.x; a5+=b1.y; a6+=b1.z; a7+=b1.w;
    }
    int dg = s1 - s0;
    float inv = 1.0f / (float)(dg > 1 ? dg : 1);
    const float4* xp = (const float4*)(x + (size_t)n * 8);
    float4 x0 = xp[0], x1v = xp[1];
    ushort* row = xa + (size_t)n * 32;
    uint4 o0 = {pack2(x0.x, x0.y), pack2(x0.z, x0.w), pack2(x1v.x, x1v.y), pack2(x1v.z, x1v.w)};
    uint4 o1 = {pack2(a0*inv, a1*inv), pack2(a2*inv, a3*inv),
                pack2(a4*inv, a5*inv), pack2(a6*inv, a7*inv)};
    uint4 z = {0u, 0u, 0u, 0u};
    *(uint4*)(row)      = o0;
    *(uint4*)(row + 8)  = o1;
    *(uint4*)(row + 16) = z;
    *(uint4*)(row + 24) = z;
}

// h1bf = bf16(xa @ Wcat1^T + b1) via one MFMA per f-tile; fp32 BN stats fused.
__global__ void __launch_bounds__(256) k_lin1(
        const ushort* __restrict__ xa, const ushort* __restrict__ Wcat1,
        const float* __restrict__ b1, ushort* __restrict__ h1bf,
        float* __restrict__ stats) {
    __shared__ ushort sOut[64 * 140];          // stride 140: 4-quad conflict-free
    __shared__ float sred[256];
    int tid = threadIdx.x;
    int wave = tid >> 6, lane = tid & 63;
    int quad = lane >> 4, l16 = lane & 15;
    int n0 = blockIdx.x * 64;

    int node = n0 + wave * 16 + l16;
    int cn = (node < N_NODES) ? node : N_NODES - 1;  // clamp; stores masked below
    B8 ta;
    ta.u = *(const uint4*)(xa + (size_t)cn * 32 + quad * 8);

    #pragma unroll
    for (int nt = 0; nt < 8; ++nt) {
        int fb = nt * 16 + l16;
        B8 tb;
        tb.u = *(const uint4*)(Wcat1 + fb * 32 + quad * 8);
        f32x4 acc = {0.f, 0.f, 0.f, 0.f};
        acc = __builtin_amdgcn_mfma_f32_16x16x32_bf16(ta.s, tb.s, acc, 0, 0, 0);
        float bb = b1[fb];
        #pragma unroll
        for (int r = 0; r < 4; ++r) {
            int row = wave * 16 + quad * 4 + r;
            sOut[row * 140 + fb] = f2bf(acc[r] + bb);
        }
    }
    __syncthreads();

    #pragma unroll
    for (int p = 0; p < 4; ++p) {
        int row = p * 16 + (tid >> 4);
        int nd = n0 + row;
        if (nd < N_NODES) {
            int c0 = (tid & 15) * 8;
            uint4 v = *(const uint4*)&sOut[row * 140 + c0];
            *(uint4*)(h1bf + (size_t)nd * F + c0) = v;
        }
    }

    int f = tid & 127, half = tid >> 7;
    float s = 0.f, s2 = 0.f;
    for (int r = half * 32; r < half * 32 + 32; ++r) {
        if (n0 + r >= N_NODES) break;
        float v = bf2f(sOut[r * 140 + f]);
        s += v; s2 += v * v;
    }
    if (half) { sred[f] = s; sred[128 + f] = s2; }
    __syncthreads();
    if (!half) {
        s += sred[f]; s2 += sred[128 + f];
        atomicAdd(&stats[f], s);
        atomicAdd(&stats[F + f], s2);
    }
}

__global__ void k_bnfin(const float* __restrict__ stats, const float* __restrict__ gamma,
                        const float* __restrict__ beta, float* __restrict__ scsh) {
    int f = threadIdx.x;
    float mu  = stats[f] * (1.0f / N_NODES);
    float var = stats[F + f] * (1.0f / N_NODES) - mu * mu;
    float sc  = gamma[f] * rsqrtf(var + BN_EPS);
    scsh[f] = sc;
    scsh[F + f] = beta[f] - mu * sc;
}

// x1bf = bf16(relu(scale*h1 + shift))
__global__ void k_bnrelu(const ushort* __restrict__ h, const float* __restrict__ scsh,
                         ushort* __restrict__ x1bf) {
    int i = blockIdx.x * 256 + threadIdx.x;      // N*128/8 = 1.6M exact
    int base = i * 8;
    int f = base & (F - 1);
    float4 sc0 = *(const float4*)(scsh + f);
    float4 sc1 = *(const float4*)(scsh + f + 4);
    float4 sh0 = *(const float4*)(scsh + F + f);
    float4 sh1 = *(const float4*)(scsh + F + f + 4);
    uint4 hv = *(const uint4*)(h + base);
    float v0 = fmaxf(0.f, bflo(hv.x)*sc0.x + sh0.x);
    float v1 = fmaxf(0.f, bfhi(hv.x)*sc0.y + sh0.y);
    float v2 = fmaxf(0.f, bflo(hv.y)*sc0.z + sh0.z);
    float v3 = fmaxf(0.f, bfhi(hv.y)*sc0.w + sh0.w);
    float v4 = fmaxf(0.f, bflo(hv.z)*sc1.x + sh1.x);
    float v5 = fmaxf(0.f, bfhi(hv.z)*sc1.y + sh1.y);
    float v6 = fmaxf(0.f, bflo(hv.w)*sc1.z + sh1.z);
    float v7 = fmaxf(0.f, bfhi(hv.w)*sc1.w + sh1.w);
    uint4 o = {pack2(v0,v1), pack2(v2,v3), pack2(v4,v5), pack2(v6,v7)};
    *(uint4*)(x1bf + base) = o;
}

// ---- layer 2 ---------------------------------------------------------------

// agg2bf[n][f] = bf16(mean over in-edges of x1bf[src][f]); 16 threads x 16B/node
__global__ void __launch_bounds__(256) k_agg2(
        const ushort* __restrict__ x1bf, const int* __restrict__ offs,
        const int* __restrict__ ssrc, ushort* __restrict__ agg2bf) {
    int t = threadIdx.x;
    int n = blockIdx.x * 16 + (t >> 4);
    int c8 = (t & 15) * 8;
    int s0 = offs[n], s1 = offs[n + 1];
    float acc[8] = {0,0,0,0,0,0,0,0};
    int j = s0;
    for (; j + 3 < s1; j += 4) {               // 4 gathers in flight
        int sa = ssrc[j], sb = ssrc[j+1], sc = ssrc[j+2], sd = ssrc[j+3];
        uint4 va = *(const uint4*)(x1bf + (size_t)sa * F + c8);
        uint4 vb = *(const uint4*)(x1bf + (size_t)sb * F + c8);
        uint4 vc = *(const uint4*)(x1bf + (size_t)sc * F + c8);
        uint4 vd = *(const uint4*)(x1bf + (size_t)sd * F + c8);
        acc[0] += (bflo(va.x)+bflo(vb.x)) + (bflo(vc.x)+bflo(vd.x));
        acc[1] += (bfhi(va.x)+bfhi(vb.x)) + (bfhi(vc.x)+bfhi(vd.x));
        acc[2] += (bflo(va.y)+bflo(vb.y)) + (bflo(vc.y)+bflo(vd.y));
        acc[3] += (bfhi(va.y)+bfhi(vb.y)) + (bfhi(vc.y)+bfhi(vd.y));
        acc[4] += (bflo(va.z)+bflo(vb.z)) + (bflo(vc.z)+bflo(vd.z));
        acc[5] += (bfhi(va.z)+bfhi(vb.z)) + (bfhi(vc.z)+bfhi(vd.z));
        acc[6] += (bflo(va.w)+bflo(vb.w)) + (bflo(vc.w)+bflo(vd.w));
        acc[7] += (bfhi(va.w)+bfhi(vb.w)) + (bfhi(vc.w)+bfhi(vd.w));
    }
    for (; j < s1; ++j) {
        uint4 v = *(const uint4*)(x1bf + (size_t)ssrc[j] * F + c8);
        acc[0] += bflo(v.x); acc[1] += bfhi(v.x);
        acc[2] += bflo(v.y); acc[3] += bfhi(v.y);
        acc[4] += bflo(v.z); acc[5] += bfhi(v.z);
        acc[6] += bflo(v.w); acc[7] += bfhi(v.w);
    }
    int dg = s1 - s0;
    float inv = 1.0f / (float)(dg > 1 ? dg : 1);
    uint4 o = {pack2(acc[0]*inv, acc[1]*inv), pack2(acc[2]*inv, acc[3]*inv),
               pack2(acc[4]*inv, acc[5]*inv), pack2(acc[6]*inv, acc[7]*inv)};
    *(uint4*)(agg2bf + (size_t)n * F + c8) = o;
}

// h2 = agg2 @ W2l^T + b2 + x1 @ W2r^T via bf16 MFMA; BN stats fused.
__global__ void __launch_bounds__(256) k_lin2(
        const ushort* __restrict__ agg2bf, const ushort* __restrict__ x1bf,
        const ushort* __restrict__ Wcat, const float* __restrict__ b2,
        ushort* __restrict__ h2bf, float* __restrict__ stats) {
    __shared__ ushort sOut[128 * 136];         // 128x128 bf16 tile, stride 136
    __shared__ float sred[256];
    int tid = threadIdx.x;
    int wave = tid >> 6, lane = tid & 63;
    int quad = lane >> 4, l16 = lane & 15;
    int n0 = blockIdx.x * 128 + wave * 32;

    s16x8 a[2][8];
    #pragma unroll
    for (int mt = 0; mt < 2; ++mt) {
        int node = n0 + mt * 16 + l16;
        if (node >= N_NODES) node = N_NODES - 1;   // clamp; stores masked below
        #pragma unroll
        for (int ks = 0; ks < 8; ++ks) {
            const ushort* src = (ks < 4) ? agg2bf : x1bf;
            B8 tm;
            tm.u = *(const uint4*)(src + (size_t)node * F + (ks & 3) * 32 + quad * 8);
            a[mt][ks] = tm.s;
        }
    }

    #pragma unroll
    for (int nt = 0; nt < 8; ++nt) {
        int fb = nt * 16 + l16;
        s16x8 b[8];
        #pragma unroll
        for (int ks = 0; ks < 8; ++ks) {
            B8 tm;
            tm.u = *(const uint4*)(Wcat + fb * 256 + ks * 32 + quad * 8);
            b[ks] = tm.s;
        }
        f32x4 acc0 = {0.f, 0.f, 0.f, 0.f};
        f32x4 acc1 = {0.f, 0.f, 0.f, 0.f};
        #pragma unroll
        for (int ks = 0; ks < 8; ++ks) {
            acc0 = __builtin_amdgcn_mfma_f32_16x16x32_bf16(a[0][ks], b[ks], acc0, 0, 0, 0);
            acc1 = __builtin_amdgcn_mfma_f32_16x16x32_bf16(a[1][ks], b[ks], acc1, 0, 0, 0);
        }
        float bb = b2[fb];
        #pragma unroll
        for (int r = 0; r < 4; ++r) {
            int row0 = wave * 32 + quad * 4 + r;          // mt = 0
            sOut[row0 * 136 + fb]        = f2bf(acc0[r] + bb);
            sOut[(row0 + 16) * 136 + fb] = f2bf(acc1[r] + bb);
        }
    }
    __syncthreads();

    #pragma unroll
    for (int p = 0; p < 8; ++p) {
        int row = p * 16 + (tid >> 4);
        int node = blockIdx.x * 128 + row;
        if (node < N_NODES) {
            int c0 = (tid & 15) * 8;
            uint4 v = *(const uint4*)&sOut[row * 136 + c0];
            *(uint4*)(h2bf + (size_t)node * F + c0) = v;
        }
    }

    int f = tid & 127, half = tid >> 7;
    float s = 0.f, s2 = 0.f;
    for (int r = half * 64; r < half * 64 + 64; ++r) {
        int node = blockIdx.x * 128 + r;
        if (node >= N_NODES) break;
        float v = bf2f(sOut[r * 136 + f]);
        s += v; s2 += v * v;
    }
    if (half) { sred[f] = s; sred[128 + f] = s2; }
    __syncthreads();
    if (!half) {
        s += sred[f]; s2 += sred[128 + f];
        atomicAdd(&stats[f], s);
        atomicAdd(&stats[F + f], s2);
    }
}

// ---- pooling ---------------------------------------------------------------

__global__ void k_pool(const ushort* __restrict__ x1bf, const ushort* __restrict__ h2bf,
                       const float* __restrict__ scsh2, const int* __restrict__ batch,
                       float* __restrict__ outacc) {
    int f = threadIdx.x;
    int n0 = blockIdx.x * 128;
    int n1 = min(n0 + 128, N_NODES);
    float sc = scsh2[f], sh = scsh2[F + f];
    float acc = 0.f;
    int curg = batch[n0];
    for (int n = n0; n < n1; ++n) {
        int g = batch[n];
        if (g != curg) {
            atomicAdd(&outacc[curg * F + f], acc);
            acc = 0.f; curg = g;
        }
        float v1 = bf2f(x1bf[(size_t)n * F + f]);
        float v2 = fmaxf(0.f, bf2f(h2bf[(size_t)n * F + f]) * sc + sh);
        acc += v1 + v2;
    }
    atomicAdd(&outacc[curg * F + f], acc);
}

__global__ void k_out(const float* __restrict__ outacc, const int* __restrict__ gstart,
                      float* __restrict__ out) {
    int i = blockIdx.x * 256 + threadIdx.x;
    if (i >= NUM_GRAPHS * F) return;
    int g = i >> 7;
    int c = gstart[g + 1] - gstart[g];
    out[i] = outacc[i] / (float)(c > 1 ? c : 1);
}

}  // namespace

extern "C" void kernel_launch(void* const* d_in, const int* in_sizes, int n_in,
                              void* d_out, int out_size, void* d_ws, size_t ws_size,
                              hipStream_t stream) {
    const float* x     = (const float*)d_in[0];
    const int*   ei    = (const int*)d_in[1];    // [2, E]: row0 = src, row1 = dst
    const int*   batch = (const int*)d_in[2];
    const float* W1l   = (const float*)d_in[3];
    const float* b1    = (const float*)d_in[4];
    const float* W1r   = (const float*)d_in[5];
    const float* g1    = (const float*)d_in[6];
    const float* be1   = (const float*)d_in[7];
    const float* W2l   = (const float*)d_in[8];
    const float* b2    = (const float*)d_in[9];
    const float* W2r   = (const float*)d_in[10];
    const float* g2    = (const float*)d_in[11];
    const float* be2   = (const float*)d_in[12];
    float* out = (float*)d_out;

    char* w = (char*)d_ws;
    size_t o = 0;
    auto alloc = [&](size_t bytes) {
        void* p = w + o;
        o += (bytes + 511) & ~(size_t)511;
        return p;
    };
    int*    offs   = (int*)alloc((size_t)(N_NODES + 1) * 4);
    int*    gcount = (int*)alloc((size_t)NBUCK * CB * 4);
    int*    bsum   = (int*)alloc((size_t)NBUCK * 4);
    int*    ssrc   = (int*)alloc((size_t)N_EDGES * 4);
    uint*   epk    = (uint*)alloc((size_t)N_EDGES * 4);
    int*    gstart = (int*)alloc((NUM_GRAPHS + 1) * 4);
    float*  stats  = (float*)alloc(512 * 4);   // [s1,s1sq | s2,s2sq]
    float*  scsh   = (float*)alloc(512 * 4);   // [sc1,sh1 | sc2,sh2]
    ushort* Wcat   = (ushort*)alloc((size_t)F * 256 * 2);
    ushort* Wcat1  = (ushort*)alloc((size_t)F * 32 * 2);
    float*  outacc = (float*)alloc((size_t)NUM_GRAPHS * F * 4);
    ushort* xa     = (ushort*)alloc((size_t)N_NODES * 32 * 2);
    ushort* h1bf   = (ushort*)alloc((size_t)N_NODES * F * 2);
    ushort* x1bf   = (ushort*)alloc((size_t)N_NODES * F * 2);
    ushort* agg2bf = (ushort*)alloc((size_t)N_NODES * F * 2);
    ushort* h2bf   = (ushort*)alloc((size_t)N_NODES * F * 2);

    hipMemsetAsync(stats,  0, 512 * 4, stream);
    hipMemsetAsync(outacc, 0, (size_t)NUM_GRAPHS * F * 4, stream);

    // CSR-by-dst: chunk bucket hist -> hierarchical scan -> partition -> rank
    k_histA<<<CB, 256, 0, stream>>>(ei, gcount);
    k_scanA<<<NBUCK, 512, 0, stream>>>(gcount, bsum);
    k_scanB<<<1, 256, 0, stream>>>(bsum);
    k_part <<<CB, 256, 0, stream>>>(ei, gcount, bsum, epk);
    k_rank <<<NBUCK, 512, 0, stream>>>(epk, bsum, offs, ssrc);
    k_bound<<<(N_NODES + 255) / 256, 256, 0, stream>>>(batch, gstart);
    k_packbf <<<64, 256, 0, stream>>>(W2l, W2r, Wcat);
    k_packbf1<<<16, 256, 0, stream>>>(W1l, W1r, Wcat1);

    // layer 1 (bf16 + MFMA; stats fused into k_lin1)
    k_agg1  <<<(N_NODES + 255) / 256, 256, 0, stream>>>(x, offs, ssrc, xa);
    k_lin1  <<<(N_NODES + 63) / 64, 256, 0, stream>>>(xa, Wcat1, b1, h1bf, stats);
    k_bnfin <<<1, 128, 0, stream>>>(stats, g1, be1, scsh);
    k_bnrelu<<<(N_NODES * F / 8) / 256, 256, 0, stream>>>(h1bf, scsh, x1bf);

    // layer 2 (bf16 + MFMA; stats fused into k_lin2)
    k_agg2  <<<N_NODES / 16, 256, 0, stream>>>(x1bf, offs, ssrc, agg2bf);
    k_lin2  <<<(N_NODES + 127) / 128, 256, 0, stream>>>(agg2bf, x1bf, Wcat, b2,
                                                        h2bf, stats + 256);
    k_bnfin <<<1, 128, 0, stream>>>(stats + 256, g2, be2, scsh + 256);

    // residual + pool
    k_pool<<<(N_NODES + 127) / 128, 128, 0, stream>>>(x1bf, h2bf, scsh + 256, batch, outacc);
    k_out <<<(NUM_GRAPHS * F + 255) / 256, 256, 0, stream>>>(outacc, gstart, out);
}